// Round 2
// baseline (84424.939 us; speedup 1.0000x reference)
//
#include <hip/hip_runtime.h>
#include <hip/hip_bf16.h>

typedef unsigned long long u64;

#define MBYTE (1ull << 20)

// ---------------- workspace layout (bytes) ----------------
static const size_t OFF_A64   = 0;                    // 1024^2 f64 (8MB)
static const size_t OFF_VT    = 8*MBYTE;              // 1024^2 f32 (4MB) reflectors transposed
static const size_t OFF_TAU   = 12*MBYTE;             // 1024 f64
static const size_t OFF_D64   = 12*MBYTE +  8192;
static const size_t OFF_E64   = 12*MBYTE + 16384;
static const size_t OFF_P64   = 12*MBYTE + 24576;
static const size_t OFF_W64   = 12*MBYTE + 32768;
static const size_t OFF_VBUF  = 12*MBYTE + 40960;
static const size_t OFF_SCD   = 12*MBYTE + 65536;     // 9216 f64 merge scratch
static const size_t OFF_SCI   = 12*MBYTE + 65536 + 73728; // 6144 int
static const size_t OFF_KN    = 12*MBYTE + 163840;    // int[8]
static const size_t OFF_KND   = 12*MBYTE + 164096;    // double[4]
static const size_t OFF_ALPHA = 12*MBYTE + 164352;    // float[8]
static const size_t OFF_QA    = 13*MBYTE;             // 4MB f32 (D&C Q, later U)
static const size_t OFF_QB    = 17*MBYTE;             // 4MB f32
static const size_t OFF_SHAT  = 21*MBYTE;             // 4MB f32
static const size_t OFF_WC    = 25*MBYTE;             // 8MB f32
static const size_t OFF_M1    = 33*MBYTE;             // 8MB f32
static const size_t OFF_T8    = 33*MBYTE;             // 2MB f32 (reuses M1, dead by then)
static const size_t OFF_ADJ   = 41*MBYTE;             // 16MB f32
static const size_t OFF_OADJ  = 17*MBYTE;             // 16MB f32 (reuses QB/SHAT/WC, dead)
static const size_t OFF_CBUF  = 0;                    // 16MB f32 (reuses A64/VT/QA, dead)

// ================= tridiagonalization (ssytd2, lower, f64) =================

__global__ void kCopyA(const float* __restrict__ A, double* __restrict__ A64) {
  int gid = blockIdx.x*256 + threadIdx.x;
  if (gid < 1024*1024) A64[gid] = (double)A[gid];
}

__global__ void kLarfg(double* A64, double* tau, double* e, double* vbuf, int i) {
  __shared__ double red[256];
  __shared__ double s_scale;
  int tid = threadIdx.x;
  double acc = 0.0;
  for (int r = i+2+tid; r < 1024; r += 256) { double v = A64[(u64)r*1024 + i]; acc += v*v; }
  red[tid] = acc; __syncthreads();
  for (int s = 128; s > 0; s >>= 1) { if (tid < s) red[tid] += red[tid+s]; __syncthreads(); }
  if (tid == 0) {
    double xn2 = red[0];
    double alpha = A64[(u64)(i+1)*1024 + i];
    if (xn2 == 0.0) { tau[i] = 0.0; e[i] = alpha; s_scale = 0.0; }
    else {
      double beta = (alpha >= 0.0) ? -sqrt(alpha*alpha + xn2) : sqrt(alpha*alpha + xn2);
      tau[i] = (beta - alpha)/beta;
      e[i] = beta;
      s_scale = 1.0/(alpha - beta);
    }
    vbuf[i+1] = 1.0;
  }
  __syncthreads();
  double sc = s_scale;
  for (int r = i+2+tid; r < 1024; r += 256) {
    double v = A64[(u64)r*1024 + i]*sc;
    A64[(u64)r*1024 + i] = v;
    vbuf[r] = v;
  }
}

__global__ void kSymv(const double* __restrict__ A64, const double* __restrict__ vbuf,
                      double* __restrict__ p, int i) {
  int wave = threadIdx.x >> 6, lane = threadIdx.x & 63;
  int r = i + 1 + blockIdx.x*4 + wave;
  if (r > 1023) return;
  const double* Arow = A64 + (u64)r*1024;
  double acc = 0.0;
  for (int c = i+1+lane; c < 1024; c += 64) acc += Arow[c]*vbuf[c];
  for (int off = 32; off > 0; off >>= 1) acc += __shfl_down(acc, off);
  if (lane == 0) p[r] = acc;
}

__global__ void kWfix(const double* __restrict__ p, const double* __restrict__ vbuf,
                      double* __restrict__ w, const double* __restrict__ tau, int i) {
  __shared__ double red[256];
  int tid = threadIdx.x;
  double acc = 0.0;
  for (int c = i+1+tid; c < 1024; c += 256) acc += p[c]*vbuf[c];
  red[tid] = acc; __syncthreads();
  for (int s = 128; s > 0; s >>= 1) { if (tid < s) red[tid] += red[tid+s]; __syncthreads(); }
  double tv = tau[i];
  double coef = 0.5*tv*tv*red[0];
  for (int c = i+1+tid; c < 1024; c += 256) w[c] = tv*p[c] - coef*vbuf[c];
}

__global__ void kRank2(double* __restrict__ A64, const double* __restrict__ vbuf,
                       const double* __restrict__ w, int i, int m) {
  int gid = blockIdx.x*256 + threadIdx.x;
  if (gid >= m*m) return;
  int rr = gid / m, cc = gid % m;
  int r = i+1+rr, c = i+1+cc;
  A64[(u64)r*1024 + c] -= vbuf[r]*w[c] + w[r]*vbuf[c];
}

__global__ void kDiag(const double* A64, double* d64) {
  int gid = blockIdx.x*256 + threadIdx.x;
  if (gid < 1024) d64[gid] = A64[(u64)gid*1024 + gid];
}

__global__ void kVtrans(const double* A64, float* Vt) {
  int gid = blockIdx.x*256 + threadIdx.x;
  if (gid >= 1024*1024) return;
  int i = gid / 1024, r = gid % 1024;
  float v;
  if (i >= 1023 || r <= i) v = 0.f;
  else if (r == i + 1) v = 1.f;
  else v = (float)A64[(u64)r*1024 + i];
  Vt[gid] = v;
}

__global__ void kCuts(double* d64, const double* e64) {
  if (threadIdx.x == 0 && blockIdx.x == 0) {
    for (int c = 16; c < 1024; c += 16) {
      double ae = fabs(e64[c-1]);
      d64[c-1] -= ae;
      d64[c]   -= ae;
    }
  }
}

// ================= ssteqr (leaves, n=16, COMPZ='I') =================

__device__ void slartg_(double f, double g, double* cs, double* sn, double* r) {
  // LAPACK >= 3.10 convention
  if (g == 0.0) { *cs = 1.0; *sn = 0.0; *r = f; }
  else if (f == 0.0) { *cs = 0.0; *sn = (g >= 0.0) ? 1.0 : -1.0; *r = fabs(g); }
  else {
    double d = sqrt(f*f + g*g);
    *cs = fabs(f)/d;
    *r = (f >= 0.0) ? d : -d;
    *sn = g / (*r);
  }
}

__device__ void slaev2_(double a, double b, double c, double* rt1, double* rt2,
                        double* cs1, double* sn1) {
  double sm = a + c, df = a - c, adf = fabs(df), tb = b + b, ab = fabs(tb);
  double acmx, acmn;
  if (fabs(a) > fabs(c)) { acmx = a; acmn = c; } else { acmx = c; acmn = a; }
  double rt;
  if (adf > ab) rt = adf*sqrt(1.0 + (ab/adf)*(ab/adf));
  else if (adf < ab) rt = ab*sqrt(1.0 + (adf/ab)*(adf/ab));
  else rt = ab*sqrt(2.0);
  int sgn1;
  if (sm < 0.0) { *rt1 = 0.5*(sm - rt); sgn1 = -1; *rt2 = (acmx / *rt1)*acmn - (b / *rt1)*b; }
  else if (sm > 0.0) { *rt1 = 0.5*(sm + rt); sgn1 = 1; *rt2 = (acmx / *rt1)*acmn - (b / *rt1)*b; }
  else { *rt1 = 0.5*rt; *rt2 = -0.5*rt; sgn1 = 1; }
  int sgn2; double cs;
  if (df >= 0.0) { cs = df + rt; sgn2 = 1; } else { cs = df - rt; sgn2 = -1; }
  double acs = fabs(cs);
  if (acs > ab) { double ct = -tb/cs; *sn1 = 1.0/sqrt(1.0 + ct*ct); *cs1 = ct*(*sn1); }
  else {
    if (ab == 0.0) { *cs1 = 1.0; *sn1 = 0.0; }
    else { double tn = -cs/tb; *cs1 = 1.0/sqrt(1.0 + tn*tn); *sn1 = tn*(*cs1); }
  }
  if (sgn1 == sgn2) { double tn = *cs1; *cs1 = -(*sn1); *sn1 = tn; }
}

__device__ void steqr16_(double* d, double* e, double* z, double* wc, double* ws_) {
  const int n = 16;
  const double eps = 5.9604644775390625e-08;   // f32 slamch('E')
  const double eps2 = eps*eps;
  const double safmin = 1.1754943508222875e-38;
  int jtot = 0; const int nmaxit = n*30;
  int l1 = 0;
  for (int outer = 0; outer < 200; ++outer) {
    if (l1 > n-1) break;
    if (l1 > 0) e[l1-1] = 0.0;
    int m = l1;
    for (; m <= n-2; ++m) {
      double tst = fabs(e[m]);
      if (tst == 0.0) break;
      if (tst <= (sqrt(fabs(d[m]))*sqrt(fabs(d[m+1])))*eps) { e[m] = 0.0; break; }
    }
    int l = l1, lend = m;
    l1 = m + 1;
    if (lend == l) continue;
    if (fabs(d[lend]) < fabs(d[l])) { int t = l; l = lend; lend = t; }
    if (lend > l) {
      // QL
      for (int it = 0; it < 800; ++it) {
        int mm = lend;
        if (l != lend) {
          for (mm = l; mm <= lend-1; ++mm) {
            double tst = e[mm]*e[mm];
            if (tst <= eps2*fabs(d[mm])*fabs(d[mm+1]) + safmin) break;
          }
        }
        if (mm < lend) e[mm] = 0.0;
        double p = d[l];
        if (mm == l) { d[l] = p; ++l; if (l <= lend) continue; break; }
        if (mm == l+1) {
          double rt1, rt2, c2, s2;
          slaev2_(d[l], e[l], d[l+1], &rt1, &rt2, &c2, &s2);
          for (int r = 0; r < n; ++r) {
            double t = z[r*16 + l + 1];
            z[r*16 + l + 1] = c2*t - s2*z[r*16 + l];
            z[r*16 + l]     = s2*t + c2*z[r*16 + l];
          }
          d[l] = rt1; d[l+1] = rt2; e[l] = 0.0;
          l += 2; if (l <= lend) continue; break;
        }
        if (jtot == nmaxit) break;
        ++jtot;
        double g = (d[l+1] - p)/(2.0*e[l]);
        double r_ = sqrt(g*g + 1.0);
        g = d[mm] - p + e[l]/(g + ((g >= 0.0) ? r_ : -r_));
        double s = 1.0, c = 1.0;
        p = 0.0;
        for (int i = mm-1; i >= l; --i) {
          double f = s*e[i], b = c*e[i];
          double cs, sn, rr;
          slartg_(g, f, &cs, &sn, &rr);
          c = cs; s = sn;
          if (i != mm-1) e[i+1] = rr;
          g = d[i+1] - p;
          rr = (d[i] - g)*s + 2.0*c*b;
          p = s*rr;
          d[i+1] = g + p;
          g = c*rr - b;
          wc[i] = c; ws_[i] = -s;
        }
        for (int jj = mm-1; jj >= l; --jj) {   // slasr 'R','V','B'
          double cs = wc[jj], sn = ws_[jj];
          for (int r = 0; r < n; ++r) {
            double t = z[r*16 + jj + 1];
            z[r*16 + jj + 1] = cs*t - sn*z[r*16 + jj];
            z[r*16 + jj]     = sn*t + cs*z[r*16 + jj];
          }
        }
        d[l] -= p;
        e[l] = g;
      }
    } else {
      // QR
      for (int it = 0; it < 800; ++it) {
        int mm = lend;
        if (l != lend) {
          for (mm = l; mm >= lend+1; --mm) {
            double tst = e[mm-1]*e[mm-1];
            if (tst <= eps2*fabs(d[mm])*fabs(d[mm-1]) + safmin) break;
          }
        }
        if (mm > lend) e[mm-1] = 0.0;
        double p = d[l];
        if (mm == l) { d[l] = p; --l; if (l >= lend) continue; break; }
        if (mm == l-1) {
          double rt1, rt2, c2, s2;
          slaev2_(d[l-1], e[l-1], d[l], &rt1, &rt2, &c2, &s2);
          for (int r = 0; r < n; ++r) {   // slasr 'F' on cols (l-1,l)
            double t = z[r*16 + l];
            z[r*16 + l]     = c2*t - s2*z[r*16 + l - 1];
            z[r*16 + l - 1] = s2*t + c2*z[r*16 + l - 1];
          }
          d[l-1] = rt1; d[l] = rt2; e[l-1] = 0.0;
          l -= 2; if (l >= lend) continue; break;
        }
        if (jtot == nmaxit) break;
        ++jtot;
        double g = (d[l-1] - p)/(2.0*e[l-1]);
        double r_ = sqrt(g*g + 1.0);
        g = d[mm] - p + e[l-1]/(g + ((g >= 0.0) ? r_ : -r_));
        double s = 1.0, c = 1.0;
        p = 0.0;
        for (int i = mm; i <= l-1; ++i) {
          double f = s*e[i], b = c*e[i];
          double cs, sn, rr;
          slartg_(g, f, &cs, &sn, &rr);
          c = cs; s = sn;
          if (i != mm) e[i-1] = rr;
          g = d[i] - p;
          rr = (d[i+1] - g)*s + 2.0*c*b;
          p = s*rr;
          d[i] = g + p;
          g = c*rr - b;
          wc[i] = c; ws_[i] = s;
        }
        for (int jj = mm; jj <= l-1; ++jj) {  // slasr 'R','V','F'
          double cs = wc[jj], sn = ws_[jj];
          for (int r = 0; r < n; ++r) {
            double t = z[r*16 + jj + 1];
            z[r*16 + jj + 1] = cs*t - sn*z[r*16 + jj];
            z[r*16 + jj]     = sn*t + cs*z[r*16 + jj];
          }
        }
        d[l] -= p;
        e[l-1] = g;
      }
    }
  }
  // ssteqr final selection sort (ascending, swap columns)
  for (int ii = 1; ii <= n-1; ++ii) {
    int i = ii - 1, k = i;
    double p = d[i];
    for (int j = ii; j <= n-1; ++j) if (d[j] < p) { k = j; p = d[j]; }
    if (k != i) {
      d[k] = d[i]; d[i] = p;
      for (int r = 0; r < n; ++r) { double t = z[r*16 + i]; z[r*16 + i] = z[r*16 + k]; z[r*16 + k] = t; }
    }
  }
}

__global__ void kLeaf(double* d64, const double* e64, float* Qa) {
  __shared__ double dd[16], ed[16], zd[256], wk1[16], wk2[16];
  int leaf = blockIdx.x, lo = leaf*16, tid = threadIdx.x;
  for (int idx = tid; idx < 256; idx += 64) zd[idx] = ((idx/16) == (idx%16)) ? 1.0 : 0.0;
  if (tid < 16) { dd[tid] = d64[lo + tid]; ed[tid] = (tid < 15) ? e64[lo + tid] : 0.0; }
  __syncthreads();
  if (tid == 0) steqr16_(dd, ed, zd, wk1, wk2);
  __syncthreads();
  for (int idx = tid; idx < 256; idx += 64) {
    int r = idx/16, c = idx%16;
    Qa[(u64)(lo + r)*1024 + lo + c] = (float)zd[idx];
  }
  if (tid < 16) d64[lo + tid] = dd[tid];
}

// ================= D&C merge (slaed1/2/3/4 analog) =================
// SCD layout (doubles): 0 z | 1024 dl | 2048 wm | 3072 mu | 4096 zh | 5120 rotc | 6144 rots | 7168 dval | 8192 dloc
// SCI layout (ints):    0 permsec | 1024 deflc | 2048 rotp | 3072 rotq | 4096 rootpos | 5120 dpos

__global__ __launch_bounds__(1024) void kDeflate(const float* __restrict__ Qa,
      const double* __restrict__ d64, const double* __restrict__ e64,
      double* scd, int* sci, int* kn, double* knd, int lo, int n1, int n) {
  __shared__ int sIdx[1024];
  double* z    = scd;
  double* dl   = scd + 1024;
  double* wm   = scd + 2048;
  double* rc   = scd + 5120;
  double* rs   = scd + 6144;
  double* dval = scd + 7168;
  double* dloc = scd + 8192;
  int* permsec = sci;
  int* deflc   = sci + 1024;
  int* rp      = sci + 2048;
  int* rq      = sci + 3072;
  int tid = threadIdx.x;
  for (int j = tid; j < n; j += blockDim.x) {
    int row = (j < n1) ? (lo + n1 - 1) : (lo + n1);
    z[j] = (double)Qa[(u64)row*1024 + lo + j];
    dloc[j] = d64[lo + j];
  }
  __syncthreads();
  if (tid == 0) {
    double rho_in = e64[lo + n1 - 1];
    if (rho_in < 0.0) for (int j = n1; j < n; ++j) z[j] = -z[j];
    const double invs2 = 0.70710678118654752440;
    for (int j = 0; j < n; ++j) z[j] *= invs2;
    double rho = fabs(2.0*rho_in);
    int i1 = 0, i2 = n1;
    for (int pos = 0; pos < n; ++pos) {
      if (i1 < n1 && (i2 >= n || dloc[i1] <= dloc[i2])) sIdx[pos] = i1++;
      else sIdx[pos] = i2++;
    }
    double zmax = 0.0, dmax = 0.0;
    for (int j = 0; j < n; ++j) { zmax = fmax(zmax, fabs(z[j])); dmax = fmax(dmax, fabs(dloc[j])); }
    double tol = 8.0*5.9604644775390625e-8*fmax(dmax, zmax);
    int K = 0, nrot = 0, nd = 0;
    if (rho*zmax <= tol) {
      for (int pos = 0; pos < n; ++pos) { int c = sIdx[pos]; deflc[nd] = c; dval[nd] = dloc[c]; nd++; }
    } else {
      int pj = -1, jpos = 0;
      for (; jpos < n; ++jpos) {
        int nj = sIdx[jpos];
        if (rho*fabs(z[nj]) <= tol) { deflc[nd] = nj; dval[nd] = dloc[nj]; nd++; }
        else { pj = nj; break; }
      }
      for (++jpos; jpos < n; ++jpos) {
        int nj = sIdx[jpos];
        if (rho*fabs(z[nj]) <= tol) { deflc[nd] = nj; dval[nd] = dloc[nj]; nd++; continue; }
        double s_ = z[pj], c_ = z[nj];
        double tu = sqrt(c_*c_ + s_*s_);
        double tdif = dloc[nj] - dloc[pj];
        c_ /= tu; s_ = -s_/tu;
        if (fabs(tdif*c_*s_) <= tol) {
          z[nj] = tu; z[pj] = 0.0;
          rp[nrot] = pj; rq[nrot] = nj; rc[nrot] = c_; rs[nrot] = s_; nrot++;
          double t1 = dloc[pj]*c_*c_ + dloc[nj]*s_*s_;
          dloc[nj] = dloc[pj]*s_*s_ + dloc[nj]*c_*c_;
          dloc[pj] = t1;
          deflc[nd] = pj; dval[nd] = t1; nd++;
          pj = nj;
        } else {
          permsec[K] = pj; dl[K] = dloc[pj]; wm[K] = z[pj]; K++;
          pj = nj;
        }
      }
      permsec[K] = pj; dl[K] = dloc[pj]; wm[K] = z[pj]; K++;
    }
    double sw2 = 0.0;
    for (int q2 = 0; q2 < K; ++q2) sw2 += wm[q2]*wm[q2];
    kn[0] = K; kn[1] = nrot; kn[2] = nd;
    knd[0] = rho; knd[1] = sw2;
  }
}

__global__ void kRots(float* Qa, const double* scd, const int* sci, const int* kn, int lo, int n) {
  int rloc = blockIdx.x*256 + threadIdx.x;
  if (rloc >= n) return;
  int nrot = kn[1];
  const double* rc = scd + 5120;
  const double* rs = scd + 6144;
  const int* rp = sci + 2048;
  const int* rq = sci + 3072;
  u64 row = (u64)(lo + rloc)*1024;
  for (int t = 0; t < nrot; ++t) {
    int p = lo + rp[t], q = lo + rq[t];
    double c = rc[t], s = rs[t];
    double x = (double)Qa[row + p], y = (double)Qa[row + q];
    Qa[row + p] = (float)(c*x + s*y);
    Qa[row + q] = (float)(c*y - s*x);
  }
}

__global__ void kSecular(double* scd, const int* kn, const double* knd, int n) {
  int i = blockIdx.x*64 + threadIdx.x;
  int K = kn[0];
  if (i >= K) return;
  const double* dl = scd + 1024;
  const double* wm = scd + 2048;
  double* mu = scd + 3072;
  double rho = knd[0], sw2 = knd[1];
  double di = dl[i];
  double hi = (i < K-1) ? (dl[i+1] - di) : (rho*sw2*(1.0 + 1e-12) + 1e-300);
  double lo_ = 0.0;
  for (int it = 0; it < 100; ++it) {
    double mid = 0.5*(lo_ + hi);
    double g = 1.0;
    for (int j = 0; j < K; ++j) g += rho*wm[j]*wm[j]/((dl[j] - di) - mid);
    if (g < 0.0) lo_ = mid; else hi = mid;
  }
  mu[i] = 0.5*(lo_ + hi);
}

__global__ void kZhat(double* scd, const int* kn, int n) {
  int j = blockIdx.x*64 + threadIdx.x;
  int K = kn[0];
  if (j >= K) return;
  const double* dl = scd + 1024;
  const double* wm = scd + 2048;
  const double* mu = scd + 3072;
  double* zh = scd + 4096;
  double dj = dl[j];
  double prod = mu[j];
  for (int i2 = 0; i2 < K; ++i2) {
    if (i2 == j) continue;
    double dd = dl[i2] - dj;
    prod *= (dd + mu[i2]) / dd;
  }
  prod = fabs(prod);
  zh[j] = (wm[j] >= 0.0) ? sqrt(prod) : -sqrt(prod);   // sign(zhat)=sign(z)  [Gu-Eisenstat]
}

__global__ void kSvecNorm(float* __restrict__ Shat, const double* scd, const int* kn, int n) {
  int i = blockIdx.x;
  int K = kn[0];
  if (i >= K) return;
  const double* dl = scd + 1024;
  const double* mu = scd + 3072;
  const double* zh = scd + 4096;
  __shared__ double red[256];
  int tid = threadIdx.x;
  double di = dl[i], m = mu[i];
  double acc = 0.0;
  for (int j = tid; j < K; j += 256) {
    double v = zh[j]/((dl[j] - di) - m);
    acc += v*v;
  }
  red[tid] = acc; __syncthreads();
  for (int s = 128; s > 0; s >>= 1) { if (tid < s) red[tid] += red[tid+s]; __syncthreads(); }
  double inv = 1.0/sqrt(red[0]);
  for (int j = tid; j < K; j += 256) {
    double v = zh[j]/((dl[j] - di) - m);
    Shat[(u64)j*1024 + i] = (float)(v*inv);
  }
}

__global__ __launch_bounds__(1024) void kSortPerm(double* scd, int* sci, const int* kn,
                                                  double* d64, int lo, int n) {
  __shared__ double sv[1024];
  __shared__ int si[1024];
  int tid = threadIdx.x;
  int K = kn[0];
  const double* dl = scd + 1024;
  const double* mu = scd + 3072;
  const double* dval = scd + 7168;
  int* rootpos = sci + 4096;
  int* dpos    = sci + 5120;
  double v;
  if (tid < K) v = dl[tid] + mu[tid];
  else if (tid < n) v = dval[tid - K];
  else v = 1e300;
  sv[tid] = v; si[tid] = tid;
  __syncthreads();
  for (int k = 2; k <= 1024; k <<= 1) {
    for (int j = k >> 1; j > 0; j >>= 1) {
      int ixj = tid ^ j;
      if (ixj > tid) {
        bool up = ((tid & k) == 0);
        double a = sv[tid], b = sv[ixj];
        int ia = si[tid], ib = si[ixj];
        bool agtb = (a > b) || (a == b && ia > ib);
        if (up ? agtb : !agtb) { sv[tid] = b; sv[ixj] = a; si[tid] = ib; si[ixj] = ia; }
      }
      __syncthreads();
    }
  }
  if (tid < n) {
    int s = si[tid];
    if (s < K) rootpos[s] = tid; else dpos[s - K] = tid;
    d64[lo + tid] = sv[tid];
  }
}

__global__ void kGather(const float* Qa, float* Qb, const int* sci, const int* kn, int lo, int n) {
  int gid = blockIdx.x*256 + threadIdx.x;
  if (gid >= n*n) return;
  int p = gid % n, r = gid / n;
  int K = kn[0];
  const int* permsec = sci;
  const int* deflc = sci + 1024;
  int src = (p < K) ? permsec[p] : deflc[p - K];
  Qb[(u64)(lo + r)*1024 + p] = Qa[(u64)(lo + r)*1024 + lo + src];
}

__global__ void kGemmMerge(const float* __restrict__ Qb, const float* __restrict__ Shat,
                           float* __restrict__ Qa, const int* sci, const int* kn, int lo, int n) {
  __shared__ float As[16][17], Bs[16][17];
  int K = kn[0];
  int tx = threadIdx.x, ty = threadIdx.y;
  int r0 = blockIdx.y*16, c0 = blockIdx.x*16;
  const int* rootpos = sci + 4096;
  float acc = 0.f;
  for (int k0 = 0; k0 < K; k0 += 16) {
    As[ty][tx] = (k0 + tx < K) ? Qb[(u64)(lo + r0 + ty)*1024 + k0 + tx] : 0.f;
    Bs[ty][tx] = (k0 + ty < K && c0 + tx < K) ? Shat[(u64)(k0 + ty)*1024 + c0 + tx] : 0.f;
    __syncthreads();
    #pragma unroll
    for (int kk = 0; kk < 16; ++kk) acc += As[ty][kk]*Bs[kk][tx];
    __syncthreads();
  }
  int i = c0 + tx;
  if (i < K) Qa[(u64)(lo + r0 + ty)*1024 + lo + rootpos[i]] = acc;
}

__global__ void kScatterDefl(const float* Qb, float* Qa, const int* sci, const int* kn, int lo, int n) {
  int gid = blockIdx.x*256 + threadIdx.x;
  if (gid >= n*n) return;
  int p = gid % n, r = gid / n;
  int K = kn[0], nd = kn[2];
  if (p < K || p - K >= nd) return;
  const int* dpos = sci + 5120;
  Qa[(u64)(lo + r)*1024 + lo + dpos[p - K]] = Qb[(u64)(lo + r)*1024 + p];
}

// ================= back-transform: U = H_0 H_1 ... H_1022 Z =================
__global__ void kBackx(float* __restrict__ Qa, const float* __restrict__ Vt,
                       const double* __restrict__ tau) {
  __shared__ double red[256];
  __shared__ double stot[16];
  int tid = threadIdx.x;
  int cix = tid & 15, strip = tid >> 4;
  int col = blockIdx.x*16 + cix;
  for (int i = 1022; i >= 0; --i) {
    int m0 = i + 1;
    double s = 0.0;
    for (int r = m0 + strip; r < 1024; r += 16)
      s += (double)Vt[(u64)i*1024 + r] * (double)Qa[(u64)r*1024 + col];
    red[tid] = s;
    __syncthreads();
    if (tid < 16) {
      double tot = 0.0;
      for (int u = 0; u < 16; ++u) tot += red[u*16 + tid];
      stot[tid] = tot * tau[i];
    }
    __syncthreads();
    double f = stot[cix];
    for (int r = m0 + strip; r < 1024; r += 16)
      Qa[(u64)r*1024 + col] -= (float)(f * (double)Vt[(u64)i*1024 + r]);
    __syncthreads();
  }
}

// ================= downstream math =================

template<int TA, int TB>
__global__ __launch_bounds__(256) void gemm_f32(const float* __restrict__ A,
    const float* __restrict__ B, float* __restrict__ C,
    int M, int N, int Kd, int lda, int ldb, int ldc) {
  __shared__ float As[16][66];
  __shared__ float Bs[16][66];
  int tid = threadIdx.x;
  int bi = blockIdx.y*64, bj = blockIdx.x*64;
  int tr = tid >> 4, tc = tid & 15;
  float acc[4][4] = {{0.f}};
  for (int k0 = 0; k0 < Kd; k0 += 16) {
    if (TA == 0) {
      int kk = tid & 15, r = tid >> 4;
      #pragma unroll
      for (int u = 0; u < 4; ++u)
        As[kk][r + 16*u] = A[(u64)(bi + r + 16*u)*lda + k0 + kk];
    } else {
      int ii = tid & 63, kk = tid >> 6;
      #pragma unroll
      for (int u = 0; u < 4; ++u)
        As[kk + 4*u][ii] = A[(u64)(k0 + kk + 4*u)*lda + bi + ii];
    }
    if (TB == 0) {
      int jj = tid & 63, kk = tid >> 6;
      #pragma unroll
      for (int u = 0; u < 4; ++u)
        Bs[kk + 4*u][jj] = B[(u64)(k0 + kk + 4*u)*ldb + bj + jj];
    } else {
      int kk = tid & 15, j = tid >> 4;
      #pragma unroll
      for (int u = 0; u < 4; ++u)
        Bs[kk][j + 16*u] = B[(u64)(bj + j + 16*u)*ldb + k0 + kk];
    }
    __syncthreads();
    #pragma unroll
    for (int kk = 0; kk < 16; ++kk) {
      float a[4], b[4];
      #pragma unroll
      for (int u = 0; u < 4; ++u) { a[u] = As[kk][tr*4 + u]; b[u] = Bs[kk][tc*4 + u]; }
      #pragma unroll
      for (int x = 0; x < 4; ++x)
        #pragma unroll
        for (int y = 0; y < 4; ++y) acc[x][y] += a[x]*b[y];
    }
    __syncthreads();
  }
  #pragma unroll
  for (int x = 0; x < 4; ++x) {
    float4 v = make_float4(acc[x][0], acc[x][1], acc[x][2], acc[x][3]);
    *(float4*)&C[(u64)(bi + tr*4 + x)*ldc + bj + tc*4] = v;
  }
}

__global__ void kWc(const float* W, float* Wc) {
  int gid = blockIdx.x*256 + threadIdx.x;
  if (gid >= 2048*1024) return;
  int i = gid >> 10, k = gid & 1023;
  Wc[gid] = W[(u64)i*2048 + k] + W[(u64)i*2048 + 1024 + k];
}

__global__ void kAbsDiag(float* adj) {
  int gid = blockIdx.x*256 + threadIdx.x;
  if (gid >= 2048*2048) return;
  int i = gid >> 11, j = gid & 2047;
  float v = fabsf(adj[gid]);
  adj[gid] = (i == j) ? 1.0f : v;
}

__global__ void kTk(const float* __restrict__ adj, const float* __restrict__ masks,
                    const float* __restrict__ Us, float* __restrict__ t8) {
  int k = blockIdx.y;
  int i = blockIdx.x*16 + (threadIdx.x >> 4);
  int r = threadIdx.x & 15;
  const float* arow = adj + (u64)i*2048;
  const float* mrow = masks + ((u64)k*2048 + i)*2048;
  const float* uk = Us + (u64)k*2048*16 + r;
  float acc = 0.f;
  for (int j = 0; j < 2048; ++j) acc += arow[j]*mrow[j]*uk[(u64)j*16];
  t8[((u64)k*2048 + i)*16 + r] = acc;
}

__global__ void kAlpha(const float* alphas, float* alpha) {
  if (threadIdx.x == 0 && blockIdx.x == 0) {
    float m = alphas[0];
    for (int k = 1; k < 8; ++k) m = fmaxf(m, alphas[k]);
    float e[8]; float s = 0.f;
    for (int k = 0; k < 8; ++k) { e[k] = expf(alphas[k] - m); s += e[k]; }
    for (int k = 0; k < 8; ++k) alpha[k] = e[k]/s;
  }
}

__global__ void kOutAdj(const float* __restrict__ adj, const float* __restrict__ masks,
                        const float* __restrict__ Vs, const float* __restrict__ t8,
                        const float* __restrict__ alpha, float* __restrict__ oadj,
                        float* __restrict__ out0) {
  __shared__ float tS[8][16][16];
  __shared__ float vS[8][16][16];
  int j0 = blockIdx.x*16, i0 = blockIdx.y*16;
  int tid = threadIdx.x;
  for (int idx = tid; idx < 2048; idx += 256) {
    int k = idx >> 8, rem = idx & 255, row = rem >> 4, r = rem & 15;
    tS[k][row][r] = t8[((u64)k*2048 + i0 + row)*16 + r];
    vS[k][row][r] = Vs[((u64)k*2048 + j0 + row)*16 + r];
  }
  __syncthreads();
  int ii = tid >> 4, jj = tid & 15;
  int i = i0 + ii, j = j0 + jj;
  float corr = 0.f;
  for (int k = 0; k < 8; ++k) {
    float m = masks[((u64)k*2048 + i)*2048 + j];
    float dv = 0.f;
    #pragma unroll
    for (int r = 0; r < 16; ++r) dv += tS[k][ii][r]*vS[k][jj][r];
    corr += alpha[k]*m*dv;
  }
  float val = adj[(u64)i*2048 + j] + corr;
  oadj[(u64)i*2048 + j] = val;
  out0[(u64)i*2048 + j] = val;
}

__global__ void kFinal(const float* __restrict__ C, float* __restrict__ out1) {
  int gid = blockIdx.x*256 + threadIdx.x;
  if (gid >= 2048*2048) return;
  int i = gid >> 11, j = gid & 2047;
  float v;
  if (i == j) v = 1.0f;
  else v = 0.5f*(C[gid] + C[(u64)j*2048 + i]);
  out1[gid] = fabsf(v);
}

// ================= host =================

extern "C" void kernel_launch(void* const* d_in, const int* in_sizes, int n_in,
                              void* d_out, int out_size, void* d_ws, size_t ws_size,
                              hipStream_t stream) {
  const float* A      = (const float*)d_in[0];
  const float* X      = (const float*)d_in[1];
  const float* W      = (const float*)d_in[2];
  const float* Us     = (const float*)d_in[3];
  const float* Vs     = (const float*)d_in[4];
  const float* alphas = (const float*)d_in[5];
  const float* masks  = (const float*)d_in[6];

  char* ws = (char*)d_ws;
  double* A64  = (double*)(ws + OFF_A64);
  float*  Vt   = (float*) (ws + OFF_VT);
  double* tau  = (double*)(ws + OFF_TAU);
  double* d64  = (double*)(ws + OFF_D64);
  double* e64  = (double*)(ws + OFF_E64);
  double* p64  = (double*)(ws + OFF_P64);
  double* w64  = (double*)(ws + OFF_W64);
  double* vbuf = (double*)(ws + OFF_VBUF);
  double* SCD  = (double*)(ws + OFF_SCD);
  int*    SCI  = (int*)   (ws + OFF_SCI);
  int*    KN   = (int*)   (ws + OFF_KN);
  double* KND  = (double*)(ws + OFF_KND);
  float*  ALPH = (float*) (ws + OFF_ALPHA);
  float*  Qa   = (float*) (ws + OFF_QA);
  float*  Qb   = (float*) (ws + OFF_QB);
  float*  Shat = (float*) (ws + OFF_SHAT);
  float*  Wc   = (float*) (ws + OFF_WC);
  float*  M1   = (float*) (ws + OFF_M1);
  float*  T8   = (float*) (ws + OFF_T8);
  float*  ADJ  = (float*) (ws + OFF_ADJ);
  float*  OADJ = (float*) (ws + OFF_OADJ);
  float*  CB   = (float*) (ws + OFF_CBUF);

  float* out0 = (float*)d_out;                 // reference outputs are float32
  float* out1 = out0 + (u64)2048*2048;

  // --- tridiagonalization (Householder, lower, f64) ---
  kCopyA<<<4096, 256, 0, stream>>>(A, A64);
  for (int i = 0; i < 1023; ++i) {
    int m = 1023 - i;
    kLarfg<<<1, 256, 0, stream>>>(A64, tau, e64, vbuf, i);
    kSymv<<<(m + 3)/4, 256, 0, stream>>>(A64, vbuf, p64, i);
    kWfix<<<1, 256, 0, stream>>>(p64, vbuf, w64, tau, i);
    kRank2<<<(m*m + 255)/256, 256, 0, stream>>>(A64, vbuf, w64, i, m);
  }
  kDiag<<<4, 256, 0, stream>>>(A64, d64);
  kVtrans<<<4096, 256, 0, stream>>>(A64, Vt);

  // --- D&C: cuts, leaves, merges ---
  kCuts<<<1, 64, 0, stream>>>(d64, e64);
  hipMemsetAsync(Qa, 0, (size_t)4*MBYTE, stream);
  kLeaf<<<64, 64, 0, stream>>>(d64, e64, Qa);

  for (int lvl = 0; lvl < 6; ++lvl) {
    int bs = 16 << lvl;
    int nm = 2*bs;
    int cnt = 1024/nm;
    for (int mg = 0; mg < cnt; ++mg) {
      int lo = mg*nm;
      kDeflate<<<1, 1024, 0, stream>>>(Qa, d64, e64, SCD, SCI, KN, KND, lo, bs, nm);
      kRots<<<(nm + 255)/256, 256, 0, stream>>>(Qa, SCD, SCI, KN, lo, nm);
      kSecular<<<(nm + 63)/64, 64, 0, stream>>>(SCD, KN, KND, nm);
      kZhat<<<(nm + 63)/64, 64, 0, stream>>>(SCD, KN, nm);
      kSvecNorm<<<nm, 256, 0, stream>>>(Shat, SCD, KN, nm);
      kSortPerm<<<1, 1024, 0, stream>>>(SCD, SCI, KN, d64, lo, nm);
      kGather<<<(nm*nm + 255)/256, 256, 0, stream>>>(Qa, Qb, SCI, KN, lo, nm);
      dim3 gg(nm/16, nm/16);
      kGemmMerge<<<gg, dim3(16, 16), 0, stream>>>(Qb, Shat, Qa, SCI, KN, lo, nm);
      kScatterDefl<<<(nm*nm + 255)/256, 256, 0, stream>>>(Qb, Qa, SCI, KN, lo, nm);
    }
  }

  // --- back-transform: Qa = U (eigenvectors of A, ascending) ---
  kBackx<<<64, 256, 0, stream>>>(Qa, Vt, tau);

  // --- downstream pipeline ---
  kWc<<<8192, 256, 0, stream>>>(W, Wc);
  // M1 = U^T @ X  (1024 x 2048)
  gemm_f32<1,0><<<dim3(32, 16), 256, 0, stream>>>(Qa, X, M1, 1024, 2048, 1024, 1024, 2048, 2048);
  // f_d = Wc @ M1 (2048 x 2048) -> ADJ
  gemm_f32<0,0><<<dim3(32, 32), 256, 0, stream>>>(Wc, M1, ADJ, 2048, 2048, 1024, 1024, 2048, 2048);
  kAbsDiag<<<16384, 256, 0, stream>>>(ADJ);
  kTk<<<dim3(128, 8), 256, 0, stream>>>(ADJ, masks, Us, T8);
  kAlpha<<<1, 64, 0, stream>>>(alphas, ALPH);
  kOutAdj<<<dim3(128, 128), 256, 0, stream>>>(ADJ, masks, Vs, T8, ALPH, OADJ, out0);
  // C = out_adj @ out_adj^T
  gemm_f32<0,1><<<dim3(32, 32), 256, 0, stream>>>(OADJ, OADJ, CB, 2048, 2048, 2048, 2048, 2048, 2048);
  kFinal<<<16384, 256, 0, stream>>>(CB, out1);
}

// Round 3
// 31284.299 us; speedup vs baseline: 2.6986x; 2.6986x over previous
//
#include <hip/hip_runtime.h>
#include <hip/hip_bf16.h>

typedef unsigned long long u64;

#define MBYTE (1ull << 20)

// ---------------- workspace layout (bytes) ----------------
static const size_t OFF_A64   = 0;                    // 1024^2 f64 (8MB)
static const size_t OFF_VT    = 8*MBYTE;              // 1024^2 f32 (4MB) reflectors transposed
static const size_t OFF_TAU   = 12*MBYTE;             // 1024 f64
static const size_t OFF_D64   = 12*MBYTE +  8192;
static const size_t OFF_E64   = 12*MBYTE + 16384;
static const size_t OFF_P64   = 12*MBYTE + 24576;
static const size_t OFF_W64   = 12*MBYTE + 32768;
static const size_t OFF_VBUF  = 12*MBYTE + 40960;
static const size_t OFF_XBUF  = 12*MBYTE + 49152;
static const size_t OFF_Y1    = 12*MBYTE + 57344;
static const size_t OFF_Y2    = 12*MBYTE + 65536;
static const size_t OFF_SCD   = 12*MBYTE + 73728;     // 9216 f64 merge scratch
static const size_t OFF_SCI   = 12*MBYTE + 147456;    // 6144 int
static const size_t OFF_KN    = 12*MBYTE + 172032;    // int[8]
static const size_t OFF_KND   = 12*MBYTE + 172288;    // double[4]
static const size_t OFF_ALPHA = 12*MBYTE + 172544;    // float[8]
static const size_t OFF_QA    = 13*MBYTE;             // 4MB f32 (D&C Q, later U)
static const size_t OFF_QB    = 17*MBYTE;             // 4MB f32
static const size_t OFF_SHAT  = 21*MBYTE;             // 4MB f32
static const size_t OFF_WC    = 25*MBYTE;             // 8MB f32
static const size_t OFF_M1    = 33*MBYTE;             // 8MB f32
static const size_t OFF_T8    = 33*MBYTE;             // 2MB f32 (reuses M1, dead by then)
static const size_t OFF_ADJ   = 41*MBYTE;             // 16MB f32
static const size_t OFF_OADJ  = 17*MBYTE;             // 16MB f32 (reuses QB/SHAT/WC, dead)
static const size_t OFF_CBUF  = 0;                    // 16MB f32 (reuses A64/VT/QA, dead)

// ================= tridiagonalization (ssytd2, lower, f64) =================
// Fused 2-kernel structure per reflector i:
//   kBig(i):   apply reflector i-1 (rank-2, rows/cols >= i+1) AND compute
//              y1[r]=A'[r,i+1], y2[r]=sum_{c>=i+2} A'[r,c]*x[c]; fix d64[i].
//   kSmall(i): norm/beta/tau/sc, v, P=tau*(y1+sc*y2), P.v, w, and the next
//              pivot column x'[c] = y1[c] - v[c]*w[i+1] - w[c] (analytic,
//              so column i+1 never needs updating in memory). Writes Vt row.

__global__ void kCopyA(const float* __restrict__ A, double* __restrict__ A64) {
  int gid = blockIdx.x*256 + threadIdx.x;
  if (gid < 1024*1024) A64[gid] = (double)A[gid];
}

__global__ void kInitTri(const double* __restrict__ A64, double* vbuf, double* wbuf, double* xbuf) {
  int tid = threadIdx.x;
  for (int c = tid; c < 1024; c += 256) { vbuf[c] = 0.0; wbuf[c] = 0.0; }
  for (int c = 1 + tid; c < 1024; c += 256) xbuf[c] = A64[(u64)c*1024 + 0];
}

__global__ void kBig(double* __restrict__ A64, const double* __restrict__ vbuf,
                     const double* __restrict__ wbuf, const double* __restrict__ xbuf,
                     double* __restrict__ y1, double* __restrict__ y2,
                     double* __restrict__ d64, int i) {
  if (blockIdx.x == 0 && threadIdx.x == 0)
    d64[i] = A64[(u64)i*1024 + i] - 2.0*vbuf[i]*wbuf[i];
  int wave = threadIdx.x >> 6, lane = threadIdx.x & 63;
  int r = i + 1 + blockIdx.x*4 + wave;
  if (r > 1023) return;
  double vr = vbuf[r], wr = wbuf[r];
  double* Arow = A64 + (u64)r*1024;
  double acc = 0.0, y1v = 0.0;
  for (int c = i+1+lane; c < 1024; c += 64) {
    double a = Arow[c] - vr*wbuf[c] - wr*vbuf[c];
    Arow[c] = a;
    if (c == i+1) y1v = a; else acc += a*xbuf[c];
  }
  for (int off = 32; off > 0; off >>= 1) acc += __shfl_down(acc, off);
  if (lane == 0) { y1[r] = y1v; y2[r] = acc; }
}

__global__ void kSmall(double* __restrict__ xbuf, const double* __restrict__ y1,
                       const double* __restrict__ y2, double* __restrict__ vbuf,
                       double* __restrict__ wbuf, double* __restrict__ Pbuf,
                       double* __restrict__ tauv, double* __restrict__ e64,
                       float* __restrict__ Vt, int i) {
  __shared__ double red[256];
  __shared__ double sS[4];
  int tid = threadIdx.x;
  double acc = 0.0;
  for (int c = i+2+tid; c < 1024; c += 256) { double v = xbuf[c]; acc += v*v; }
  red[tid] = acc; __syncthreads();
  for (int s = 128; s > 0; s >>= 1) { if (tid < s) red[tid] += red[tid+s]; __syncthreads(); }
  if (tid == 0) {
    double xn2 = red[0];
    double alpha = xbuf[i+1];
    double tv, sc;
    if (xn2 == 0.0) { tv = 0.0; e64[i] = alpha; sc = 0.0; }
    else {
      double beta = (alpha >= 0.0) ? -sqrt(alpha*alpha + xn2) : sqrt(alpha*alpha + xn2);
      tv = (beta - alpha)/beta;
      e64[i] = beta;
      sc = 1.0/(alpha - beta);
    }
    tauv[i] = tv;
    sS[0] = sc; sS[1] = tv;
    vbuf[i+1] = 1.0;
    Vt[(u64)i*1024 + i + 1] = 1.0f;
  }
  __syncthreads();
  double sc = sS[0], tv = sS[1];
  for (int c = i+2+tid; c < 1024; c += 256) {
    double v = xbuf[c]*sc;
    vbuf[c] = v;
    Vt[(u64)i*1024 + c] = (float)v;
  }
  __syncthreads();
  double acc2 = 0.0;
  for (int r = i+1+tid; r < 1024; r += 256) {
    double P = tv*(y1[r] + sc*y2[r]);
    Pbuf[r] = P;
    acc2 += P*vbuf[r];
  }
  red[tid] = acc2; __syncthreads();
  for (int s = 128; s > 0; s >>= 1) { if (tid < s) red[tid] += red[tid+s]; __syncthreads(); }
  if (tid == 0) sS[2] = 0.5*tv*red[0];
  __syncthreads();
  double coef = sS[2];
  for (int r = i+1+tid; r < 1024; r += 256) wbuf[r] = Pbuf[r] - coef*vbuf[r];
  __syncthreads();
  double wip1 = wbuf[i+1];
  for (int c = i+2+tid; c < 1024; c += 256)
    xbuf[c] = y1[c] - vbuf[c]*wip1 - wbuf[c];
}

__global__ void kEpi(const double* __restrict__ A64, double* __restrict__ d64) {
  if (threadIdx.x == 0 && blockIdx.x == 0) d64[1023] = A64[(u64)1023*1024 + 1023];
}

__global__ void kCuts(double* d64, const double* e64) {
  if (threadIdx.x == 0 && blockIdx.x == 0) {
    for (int c = 16; c < 1024; c += 16) {
      double ae = fabs(e64[c-1]);
      d64[c-1] -= ae;
      d64[c]   -= ae;
    }
  }
}

// ================= ssteqr (leaves, n=16, COMPZ='I') =================

__device__ void slartg_(double f, double g, double* cs, double* sn, double* r) {
  // LAPACK >= 3.10 convention
  if (g == 0.0) { *cs = 1.0; *sn = 0.0; *r = f; }
  else if (f == 0.0) { *cs = 0.0; *sn = (g >= 0.0) ? 1.0 : -1.0; *r = fabs(g); }
  else {
    double d = sqrt(f*f + g*g);
    *cs = fabs(f)/d;
    *r = (f >= 0.0) ? d : -d;
    *sn = g / (*r);
  }
}

__device__ void slaev2_(double a, double b, double c, double* rt1, double* rt2,
                        double* cs1, double* sn1) {
  double sm = a + c, df = a - c, adf = fabs(df), tb = b + b, ab = fabs(tb);
  double acmx, acmn;
  if (fabs(a) > fabs(c)) { acmx = a; acmn = c; } else { acmx = c; acmn = a; }
  double rt;
  if (adf > ab) rt = adf*sqrt(1.0 + (ab/adf)*(ab/adf));
  else if (adf < ab) rt = ab*sqrt(1.0 + (adf/ab)*(adf/ab));
  else rt = ab*sqrt(2.0);
  int sgn1;
  if (sm < 0.0) { *rt1 = 0.5*(sm - rt); sgn1 = -1; *rt2 = (acmx / *rt1)*acmn - (b / *rt1)*b; }
  else if (sm > 0.0) { *rt1 = 0.5*(sm + rt); sgn1 = 1; *rt2 = (acmx / *rt1)*acmn - (b / *rt1)*b; }
  else { *rt1 = 0.5*rt; *rt2 = -0.5*rt; sgn1 = 1; }
  int sgn2; double cs;
  if (df >= 0.0) { cs = df + rt; sgn2 = 1; } else { cs = df - rt; sgn2 = -1; }
  double acs = fabs(cs);
  if (acs > ab) { double ct = -tb/cs; *sn1 = 1.0/sqrt(1.0 + ct*ct); *cs1 = ct*(*sn1); }
  else {
    if (ab == 0.0) { *cs1 = 1.0; *sn1 = 0.0; }
    else { double tn = -cs/tb; *cs1 = 1.0/sqrt(1.0 + tn*tn); *sn1 = tn*(*cs1); }
  }
  if (sgn1 == sgn2) { double tn = *cs1; *cs1 = -(*sn1); *sn1 = tn; }
}

__device__ void steqr16_(double* d, double* e, double* z, double* wc, double* ws_) {
  const int n = 16;
  const double eps = 5.9604644775390625e-08;   // f32 slamch('E')
  const double eps2 = eps*eps;
  const double safmin = 1.1754943508222875e-38;
  int jtot = 0; const int nmaxit = n*30;
  int l1 = 0;
  for (int outer = 0; outer < 200; ++outer) {
    if (l1 > n-1) break;
    if (l1 > 0) e[l1-1] = 0.0;
    int m = l1;
    for (; m <= n-2; ++m) {
      double tst = fabs(e[m]);
      if (tst == 0.0) break;
      if (tst <= (sqrt(fabs(d[m]))*sqrt(fabs(d[m+1])))*eps) { e[m] = 0.0; break; }
    }
    int l = l1, lend = m;
    l1 = m + 1;
    if (lend == l) continue;
    if (fabs(d[lend]) < fabs(d[l])) { int t = l; l = lend; lend = t; }
    if (lend > l) {
      // QL
      for (int it = 0; it < 800; ++it) {
        int mm = lend;
        if (l != lend) {
          for (mm = l; mm <= lend-1; ++mm) {
            double tst = e[mm]*e[mm];
            if (tst <= eps2*fabs(d[mm])*fabs(d[mm+1]) + safmin) break;
          }
        }
        if (mm < lend) e[mm] = 0.0;
        double p = d[l];
        if (mm == l) { d[l] = p; ++l; if (l <= lend) continue; break; }
        if (mm == l+1) {
          double rt1, rt2, c2, s2;
          slaev2_(d[l], e[l], d[l+1], &rt1, &rt2, &c2, &s2);
          for (int r = 0; r < n; ++r) {
            double t = z[r*16 + l + 1];
            z[r*16 + l + 1] = c2*t - s2*z[r*16 + l];
            z[r*16 + l]     = s2*t + c2*z[r*16 + l];
          }
          d[l] = rt1; d[l+1] = rt2; e[l] = 0.0;
          l += 2; if (l <= lend) continue; break;
        }
        if (jtot == nmaxit) break;
        ++jtot;
        double g = (d[l+1] - p)/(2.0*e[l]);
        double r_ = sqrt(g*g + 1.0);
        g = d[mm] - p + e[l]/(g + ((g >= 0.0) ? r_ : -r_));
        double s = 1.0, c = 1.0;
        p = 0.0;
        for (int i = mm-1; i >= l; --i) {
          double f = s*e[i], b = c*e[i];
          double cs, sn, rr;
          slartg_(g, f, &cs, &sn, &rr);
          c = cs; s = sn;
          if (i != mm-1) e[i+1] = rr;
          g = d[i+1] - p;
          rr = (d[i] - g)*s + 2.0*c*b;
          p = s*rr;
          d[i+1] = g + p;
          g = c*rr - b;
          wc[i] = c; ws_[i] = -s;
        }
        for (int jj = mm-1; jj >= l; --jj) {   // slasr 'R','V','B'
          double cs = wc[jj], sn = ws_[jj];
          for (int r = 0; r < n; ++r) {
            double t = z[r*16 + jj + 1];
            z[r*16 + jj + 1] = cs*t - sn*z[r*16 + jj];
            z[r*16 + jj]     = sn*t + cs*z[r*16 + jj];
          }
        }
        d[l] -= p;
        e[l] = g;
      }
    } else {
      // QR
      for (int it = 0; it < 800; ++it) {
        int mm = lend;
        if (l != lend) {
          for (mm = l; mm >= lend+1; --mm) {
            double tst = e[mm-1]*e[mm-1];
            if (tst <= eps2*fabs(d[mm])*fabs(d[mm-1]) + safmin) break;
          }
        }
        if (mm > lend) e[mm-1] = 0.0;
        double p = d[l];
        if (mm == l) { d[l] = p; --l; if (l >= lend) continue; break; }
        if (mm == l-1) {
          double rt1, rt2, c2, s2;
          slaev2_(d[l-1], e[l-1], d[l], &rt1, &rt2, &c2, &s2);
          for (int r = 0; r < n; ++r) {   // slasr 'F' on cols (l-1,l)
            double t = z[r*16 + l];
            z[r*16 + l]     = c2*t - s2*z[r*16 + l - 1];
            z[r*16 + l - 1] = s2*t + c2*z[r*16 + l - 1];
          }
          d[l-1] = rt1; d[l] = rt2; e[l-1] = 0.0;
          l -= 2; if (l >= lend) continue; break;
        }
        if (jtot == nmaxit) break;
        ++jtot;
        double g = (d[l-1] - p)/(2.0*e[l-1]);
        double r_ = sqrt(g*g + 1.0);
        g = d[mm] - p + e[l-1]/(g + ((g >= 0.0) ? r_ : -r_));
        double s = 1.0, c = 1.0;
        p = 0.0;
        for (int i = mm; i <= l-1; ++i) {
          double f = s*e[i], b = c*e[i];
          double cs, sn, rr;
          slartg_(g, f, &cs, &sn, &rr);
          c = cs; s = sn;
          if (i != mm) e[i-1] = rr;
          g = d[i] - p;
          rr = (d[i+1] - g)*s + 2.0*c*b;
          p = s*rr;
          d[i] = g + p;
          g = c*rr - b;
          wc[i] = c; ws_[i] = s;
        }
        for (int jj = mm; jj <= l-1; ++jj) {  // slasr 'R','V','F'
          double cs = wc[jj], sn = ws_[jj];
          for (int r = 0; r < n; ++r) {
            double t = z[r*16 + jj + 1];
            z[r*16 + jj + 1] = cs*t - sn*z[r*16 + jj];
            z[r*16 + jj]     = sn*t + cs*z[r*16 + jj];
          }
        }
        d[l] -= p;
        e[l-1] = g;
      }
    }
  }
  // ssteqr final selection sort (ascending, swap columns)
  for (int ii = 1; ii <= n-1; ++ii) {
    int i = ii - 1, k = i;
    double p = d[i];
    for (int j = ii; j <= n-1; ++j) if (d[j] < p) { k = j; p = d[j]; }
    if (k != i) {
      d[k] = d[i]; d[i] = p;
      for (int r = 0; r < n; ++r) { double t = z[r*16 + i]; z[r*16 + i] = z[r*16 + k]; z[r*16 + k] = t; }
    }
  }
}

__global__ void kLeaf(double* d64, const double* e64, float* Qa) {
  __shared__ double dd[16], ed[16], zd[256], wk1[16], wk2[16];
  int leaf = blockIdx.x, lo = leaf*16, tid = threadIdx.x;
  for (int idx = tid; idx < 256; idx += 64) zd[idx] = ((idx/16) == (idx%16)) ? 1.0 : 0.0;
  if (tid < 16) { dd[tid] = d64[lo + tid]; ed[tid] = (tid < 15) ? e64[lo + tid] : 0.0; }
  __syncthreads();
  if (tid == 0) steqr16_(dd, ed, zd, wk1, wk2);
  __syncthreads();
  for (int idx = tid; idx < 256; idx += 64) {
    int r = idx/16, c = idx%16;
    Qa[(u64)(lo + r)*1024 + lo + c] = (float)zd[idx];
  }
  if (tid < 16) d64[lo + tid] = dd[tid];
}

// ================= D&C merge (slaed1/2/3/4 analog) =================
// SCD layout (doubles): 1024 dl | 2048 wm | 3072 mu | 4096 zh | 5120 rotc | 6144 rots | 7168 dval
// SCI layout (ints):    0 permsec | 1024 deflc | 2048 rotp | 3072 rotq | 4096 rootpos | 5120 dpos

__global__ __launch_bounds__(1024) void kDeflate2(const float* __restrict__ Qa,
      const double* __restrict__ d64, const double* __restrict__ e64,
      double* scd, int* sci, int* kn, double* knd, int lo, int n1, int n) {
  __shared__ double zL[1024], dlocL[1024], dlL[1024], wmL[1024], dvalL[1024];
  __shared__ int sIdxL[1024], permL[1024], deflL[1024];
  __shared__ double sSc[4];
  __shared__ int sKn[4];
  int tid = threadIdx.x;
  if (tid == 0) sSc[0] = e64[lo + n1 - 1];
  __syncthreads();
  double rho_in = sSc[0];
  const double invs2 = 0.70710678118654752440;
  if (tid < n) {
    int row = (tid < n1) ? (lo + n1 - 1) : (lo + n1);
    double s = (rho_in < 0.0 && tid >= n1) ? -invs2 : invs2;
    zL[tid] = (double)Qa[(u64)row*1024 + lo + tid] * s;
    dlocL[tid] = d64[lo + tid];
  }
  __syncthreads();
  // parallel stable merge of two sorted halves (matches serial a<=b rule)
  if (tid < n) {
    int pos;
    double key = dlocL[tid];
    if (tid < n1) {
      int loB = 0, hiB = n - n1;
      while (loB < hiB) { int mid = (loB+hiB)>>1; if (dlocL[n1+mid] < key) loB = mid+1; else hiB = mid; }
      pos = tid + loB;
    } else {
      int loA = 0, hiA = n1;
      while (loA < hiA) { int mid = (loA+hiA)>>1; if (dlocL[mid] <= key) loA = mid+1; else hiA = mid; }
      pos = (tid - n1) + loA;
    }
    sIdxL[pos] = tid;
  }
  // zmax reduction (dvalL as scratch; scan writes it later)
  dvalL[tid] = (tid < n) ? fabs(zL[tid]) : 0.0;
  __syncthreads();
  for (int s = 512; s > 0; s >>= 1) { if (tid < s) dvalL[tid] = fmax(dvalL[tid], dvalL[tid+s]); __syncthreads(); }
  if (tid == 0) sSc[1] = dvalL[0];
  __syncthreads();
  dvalL[tid] = (tid < n) ? fabs(dlocL[tid]) : 0.0;
  __syncthreads();
  for (int s = 512; s > 0; s >>= 1) { if (tid < s) dvalL[tid] = fmax(dvalL[tid], dvalL[tid+s]); __syncthreads(); }
  if (tid == 0) sSc[2] = dvalL[0];
  __syncthreads();
  if (tid == 0) {
    double zmax = sSc[1], dmax = sSc[2];
    double rho = fabs(2.0*rho_in);
    double tol = 8.0*5.9604644775390625e-8*fmax(dmax, zmax);
    double* rcG = scd + 5120;
    double* rsG = scd + 6144;
    int* rpG = sci + 2048;
    int* rqG = sci + 3072;
    int K = 0, nrot = 0, nd = 0;
    if (rho*zmax <= tol) {
      for (int pos = 0; pos < n; ++pos) { int c = sIdxL[pos]; deflL[nd] = c; dvalL[nd] = dlocL[c]; nd++; }
    } else {
      int pj = -1, jpos = 0;
      for (; jpos < n; ++jpos) {
        int nj = sIdxL[jpos];
        if (rho*fabs(zL[nj]) <= tol) { deflL[nd] = nj; dvalL[nd] = dlocL[nj]; nd++; }
        else { pj = nj; break; }
      }
      for (++jpos; jpos < n; ++jpos) {
        int nj = sIdxL[jpos];
        if (rho*fabs(zL[nj]) <= tol) { deflL[nd] = nj; dvalL[nd] = dlocL[nj]; nd++; continue; }
        double s_ = zL[pj], c_ = zL[nj];
        double tu = sqrt(c_*c_ + s_*s_);
        double tdif = dlocL[nj] - dlocL[pj];
        c_ /= tu; s_ = -s_/tu;
        if (fabs(tdif*c_*s_) <= tol) {
          zL[nj] = tu; zL[pj] = 0.0;
          rpG[nrot] = pj; rqG[nrot] = nj; rcG[nrot] = c_; rsG[nrot] = s_; nrot++;
          double t1 = dlocL[pj]*c_*c_ + dlocL[nj]*s_*s_;
          dlocL[nj] = dlocL[pj]*s_*s_ + dlocL[nj]*c_*c_;
          dlocL[pj] = t1;
          deflL[nd] = pj; dvalL[nd] = t1; nd++;
          pj = nj;
        } else {
          permL[K] = pj; dlL[K] = dlocL[pj]; wmL[K] = zL[pj]; K++;
          pj = nj;
        }
      }
      permL[K] = pj; dlL[K] = dlocL[pj]; wmL[K] = zL[pj]; K++;
    }
    sKn[0] = K; sKn[1] = nrot; sKn[2] = nd;
    kn[0] = K; kn[1] = nrot; kn[2] = nd;
    knd[0] = rho;
  }
  __syncthreads();
  int K = sKn[0], nd = sKn[2];
  // sw2 reduction (zL dead now)
  zL[tid] = (tid < K) ? wmL[tid]*wmL[tid] : 0.0;
  __syncthreads();
  for (int s = 512; s > 0; s >>= 1) { if (tid < s) zL[tid] += zL[tid+s]; __syncthreads(); }
  if (tid == 0) knd[1] = zL[0];
  if (tid < K) { scd[1024 + tid] = dlL[tid]; scd[2048 + tid] = wmL[tid]; sci[tid] = permL[tid]; }
  if (tid < nd) { scd[7168 + tid] = dvalL[tid]; sci[1024 + tid] = deflL[tid]; }
}

__global__ void kRots(float* Qa, const double* scd, const int* sci, const int* kn, int lo, int n) {
  int rloc = blockIdx.x*256 + threadIdx.x;
  if (rloc >= n) return;
  int nrot = kn[1];
  const double* rc = scd + 5120;
  const double* rs = scd + 6144;
  const int* rp = sci + 2048;
  const int* rq = sci + 3072;
  u64 row = (u64)(lo + rloc)*1024;
  for (int t = 0; t < nrot; ++t) {
    int p = lo + rp[t], q = lo + rq[t];
    double c = rc[t], s = rs[t];
    double x = (double)Qa[row + p], y = (double)Qa[row + q];
    Qa[row + p] = (float)(c*x + s*y);
    Qa[row + q] = (float)(c*y - s*x);
  }
}

// one wave per secular root, dl/wm staged in LDS
__global__ __launch_bounds__(256) void kSecular2(double* scd, const int* kn, const double* knd, int n) {
  __shared__ double dlS[1024], wmS[1024];
  int K = kn[0];
  int tid = threadIdx.x;
  for (int j = tid; j < K; j += 256) { dlS[j] = scd[1024 + j]; wmS[j] = scd[2048 + j]; }
  __syncthreads();
  int wave = tid >> 6, lane = tid & 63;
  int i = blockIdx.x*4 + wave;
  if (i >= K) return;
  double rho = knd[0], sw2 = knd[1];
  double di = dlS[i];
  double hi = (i < K-1) ? (dlS[i+1] - di) : (rho*sw2*(1.0 + 1e-12) + 1e-300);
  double lo_ = 0.0;
  for (int it = 0; it < 100; ++it) {
    double mid = 0.5*(lo_ + hi);
    double g = 0.0;
    for (int j = lane; j < K; j += 64) { double w = wmS[j]; g += w*w/((dlS[j] - di) - mid); }
    for (int off = 32; off > 0; off >>= 1) g += __shfl_xor(g, off);
    g = 1.0 + rho*g;
    if (g < 0.0) lo_ = mid; else hi = mid;
  }
  scd[3072 + i] = 0.5*(lo_ + hi);
}

__global__ void kZhat(double* scd, const int* kn, int n) {
  int j = blockIdx.x*64 + threadIdx.x;
  int K = kn[0];
  if (j >= K) return;
  const double* dl = scd + 1024;
  const double* wm = scd + 2048;
  const double* mu = scd + 3072;
  double* zh = scd + 4096;
  double dj = dl[j];
  double prod = mu[j];
  for (int i2 = 0; i2 < K; ++i2) {
    if (i2 == j) continue;
    double dd = dl[i2] - dj;
    prod *= (dd + mu[i2]) / dd;
  }
  prod = fabs(prod);
  zh[j] = (wm[j] >= 0.0) ? sqrt(prod) : -sqrt(prod);   // sign(zhat)=sign(z)  [Gu-Eisenstat]
}

__global__ void kSvecNorm(float* __restrict__ Shat, const double* scd, const int* kn, int n) {
  int i = blockIdx.x;
  int K = kn[0];
  if (i >= K) return;
  const double* dl = scd + 1024;
  const double* mu = scd + 3072;
  const double* zh = scd + 4096;
  __shared__ double red[256];
  int tid = threadIdx.x;
  double di = dl[i], m = mu[i];
  double acc = 0.0;
  for (int j = tid; j < K; j += 256) {
    double v = zh[j]/((dl[j] - di) - m);
    acc += v*v;
  }
  red[tid] = acc; __syncthreads();
  for (int s = 128; s > 0; s >>= 1) { if (tid < s) red[tid] += red[tid+s]; __syncthreads(); }
  double inv = 1.0/sqrt(red[0]);
  for (int j = tid; j < K; j += 256) {
    double v = zh[j]/((dl[j] - di) - m);
    Shat[(u64)j*1024 + i] = (float)(v*inv);
  }
}

__global__ __launch_bounds__(1024) void kSortPerm(double* scd, int* sci, const int* kn,
                                                  double* d64, int lo, int n) {
  __shared__ double sv[1024];
  __shared__ int si[1024];
  int tid = threadIdx.x;
  int K = kn[0];
  const double* dl = scd + 1024;
  const double* mu = scd + 3072;
  const double* dval = scd + 7168;
  int* rootpos = sci + 4096;
  int* dpos    = sci + 5120;
  double v;
  if (tid < K) v = dl[tid] + mu[tid];
  else if (tid < n) v = dval[tid - K];
  else v = 1e300;
  sv[tid] = v; si[tid] = tid;
  __syncthreads();
  for (int k = 2; k <= 1024; k <<= 1) {
    for (int j = k >> 1; j > 0; j >>= 1) {
      int ixj = tid ^ j;
      if (ixj > tid) {
        bool up = ((tid & k) == 0);
        double a = sv[tid], b = sv[ixj];
        int ia = si[tid], ib = si[ixj];
        bool agtb = (a > b) || (a == b && ia > ib);
        if (up ? agtb : !agtb) { sv[tid] = b; sv[ixj] = a; si[tid] = ib; si[ixj] = ia; }
      }
      __syncthreads();
    }
  }
  if (tid < n) {
    int s = si[tid];
    if (s < K) rootpos[s] = tid; else dpos[s - K] = tid;
    d64[lo + tid] = sv[tid];
  }
}

__global__ void kGather(const float* Qa, float* Qb, const int* sci, const int* kn, int lo, int n) {
  int gid = blockIdx.x*256 + threadIdx.x;
  if (gid >= n*n) return;
  int p = gid % n, r = gid / n;
  int K = kn[0];
  const int* permsec = sci;
  const int* deflc = sci + 1024;
  int src = (p < K) ? permsec[p] : deflc[p - K];
  Qb[(u64)(lo + r)*1024 + p] = Qa[(u64)(lo + r)*1024 + lo + src];
}

__global__ void kGemmMerge(const float* __restrict__ Qb, const float* __restrict__ Shat,
                           float* __restrict__ Qa, const int* sci, const int* kn, int lo, int n) {
  __shared__ float As[16][17], Bs[16][17];
  int K = kn[0];
  int tx = threadIdx.x, ty = threadIdx.y;
  int r0 = blockIdx.y*16, c0 = blockIdx.x*16;
  const int* rootpos = sci + 4096;
  float acc = 0.f;
  for (int k0 = 0; k0 < K; k0 += 16) {
    As[ty][tx] = (k0 + tx < K) ? Qb[(u64)(lo + r0 + ty)*1024 + k0 + tx] : 0.f;
    Bs[ty][tx] = (k0 + ty < K && c0 + tx < K) ? Shat[(u64)(k0 + ty)*1024 + c0 + tx] : 0.f;
    __syncthreads();
    #pragma unroll
    for (int kk = 0; kk < 16; ++kk) acc += As[ty][kk]*Bs[kk][tx];
    __syncthreads();
  }
  int i = c0 + tx;
  if (i < K) Qa[(u64)(lo + r0 + ty)*1024 + lo + rootpos[i]] = acc;
}

__global__ void kScatterDefl(const float* Qb, float* Qa, const int* sci, const int* kn, int lo, int n) {
  int gid = blockIdx.x*256 + threadIdx.x;
  if (gid >= n*n) return;
  int p = gid % n, r = gid / n;
  int K = kn[0], nd = kn[2];
  if (p < K || p - K >= nd) return;
  const int* dpos = sci + 5120;
  Qa[(u64)(lo + r)*1024 + lo + dpos[p - K]] = Qb[(u64)(lo + r)*1024 + p];
}

// ================= back-transform: U = H_0 H_1 ... H_1022 Z =================
__global__ void kBackx(float* __restrict__ Qa, const float* __restrict__ Vt,
                       const double* __restrict__ tau) {
  __shared__ double red[256];
  __shared__ double stot[16];
  int tid = threadIdx.x;
  int cix = tid & 15, strip = tid >> 4;
  int col = blockIdx.x*16 + cix;
  for (int i = 1022; i >= 0; --i) {
    int m0 = i + 1;
    double s = 0.0;
    for (int r = m0 + strip; r < 1024; r += 16)
      s += (double)Vt[(u64)i*1024 + r] * (double)Qa[(u64)r*1024 + col];
    red[tid] = s;
    __syncthreads();
    if (tid < 16) {
      double tot = 0.0;
      for (int u = 0; u < 16; ++u) tot += red[u*16 + tid];
      stot[tid] = tot * tau[i];
    }
    __syncthreads();
    double f = stot[cix];
    for (int r = m0 + strip; r < 1024; r += 16)
      Qa[(u64)r*1024 + col] -= (float)(f * (double)Vt[(u64)i*1024 + r]);
    __syncthreads();
  }
}

// ================= downstream math =================

template<int TA, int TB>
__global__ __launch_bounds__(256) void gemm_f32(const float* __restrict__ A,
    const float* __restrict__ B, float* __restrict__ C,
    int M, int N, int Kd, int lda, int ldb, int ldc) {
  __shared__ float As[16][66];
  __shared__ float Bs[16][66];
  int tid = threadIdx.x;
  int bi = blockIdx.y*64, bj = blockIdx.x*64;
  int tr = tid >> 4, tc = tid & 15;
  float acc[4][4] = {{0.f}};
  for (int k0 = 0; k0 < Kd; k0 += 16) {
    if (TA == 0) {
      int kk = tid & 15, r = tid >> 4;
      #pragma unroll
      for (int u = 0; u < 4; ++u)
        As[kk][r + 16*u] = A[(u64)(bi + r + 16*u)*lda + k0 + kk];
    } else {
      int ii = tid & 63, kk = tid >> 6;
      #pragma unroll
      for (int u = 0; u < 4; ++u)
        As[kk + 4*u][ii] = A[(u64)(k0 + kk + 4*u)*lda + bi + ii];
    }
    if (TB == 0) {
      int jj = tid & 63, kk = tid >> 6;
      #pragma unroll
      for (int u = 0; u < 4; ++u)
        Bs[kk + 4*u][jj] = B[(u64)(k0 + kk + 4*u)*ldb + bj + jj];
    } else {
      int kk = tid & 15, j = tid >> 4;
      #pragma unroll
      for (int u = 0; u < 4; ++u)
        Bs[kk][j + 16*u] = B[(u64)(bj + j + 16*u)*ldb + k0 + kk];
    }
    __syncthreads();
    #pragma unroll
    for (int kk = 0; kk < 16; ++kk) {
      float a[4], b[4];
      #pragma unroll
      for (int u = 0; u < 4; ++u) { a[u] = As[kk][tr*4 + u]; b[u] = Bs[kk][tc*4 + u]; }
      #pragma unroll
      for (int x = 0; x < 4; ++x)
        #pragma unroll
        for (int y = 0; y < 4; ++y) acc[x][y] += a[x]*b[y];
    }
    __syncthreads();
  }
  #pragma unroll
  for (int x = 0; x < 4; ++x) {
    float4 v = make_float4(acc[x][0], acc[x][1], acc[x][2], acc[x][3]);
    *(float4*)&C[(u64)(bi + tr*4 + x)*ldc + bj + tc*4] = v;
  }
}

__global__ void kWc(const float* W, float* Wc) {
  int gid = blockIdx.x*256 + threadIdx.x;
  if (gid >= 2048*1024) return;
  int i = gid >> 10, k = gid & 1023;
  Wc[gid] = W[(u64)i*2048 + k] + W[(u64)i*2048 + 1024 + k];
}

__global__ void kAbsDiag(float* adj) {
  int gid = blockIdx.x*256 + threadIdx.x;
  if (gid >= 2048*2048) return;
  int i = gid >> 11, j = gid & 2047;
  float v = fabsf(adj[gid]);
  adj[gid] = (i == j) ? 1.0f : v;
}

__global__ void kTk(const float* __restrict__ adj, const float* __restrict__ masks,
                    const float* __restrict__ Us, float* __restrict__ t8) {
  int k = blockIdx.y;
  int i = blockIdx.x*16 + (threadIdx.x >> 4);
  int r = threadIdx.x & 15;
  const float* arow = adj + (u64)i*2048;
  const float* mrow = masks + ((u64)k*2048 + i)*2048;
  const float* uk = Us + (u64)k*2048*16 + r;
  float acc = 0.f;
  for (int j = 0; j < 2048; ++j) acc += arow[j]*mrow[j]*uk[(u64)j*16];
  t8[((u64)k*2048 + i)*16 + r] = acc;
}

__global__ void kAlpha(const float* alphas, float* alpha) {
  if (threadIdx.x == 0 && blockIdx.x == 0) {
    float m = alphas[0];
    for (int k = 1; k < 8; ++k) m = fmaxf(m, alphas[k]);
    float e[8]; float s = 0.f;
    for (int k = 0; k < 8; ++k) { e[k] = expf(alphas[k] - m); s += e[k]; }
    for (int k = 0; k < 8; ++k) alpha[k] = e[k]/s;
  }
}

__global__ void kOutAdj(const float* __restrict__ adj, const float* __restrict__ masks,
                        const float* __restrict__ Vs, const float* __restrict__ t8,
                        const float* __restrict__ alpha, float* __restrict__ oadj,
                        float* __restrict__ out0) {
  __shared__ float tS[8][16][16];
  __shared__ float vS[8][16][16];
  int j0 = blockIdx.x*16, i0 = blockIdx.y*16;
  int tid = threadIdx.x;
  for (int idx = tid; idx < 2048; idx += 256) {
    int k = idx >> 8, rem = idx & 255, row = rem >> 4, r = rem & 15;
    tS[k][row][r] = t8[((u64)k*2048 + i0 + row)*16 + r];
    vS[k][row][r] = Vs[((u64)k*2048 + j0 + row)*16 + r];
  }
  __syncthreads();
  int ii = tid >> 4, jj = tid & 15;
  int i = i0 + ii, j = j0 + jj;
  float corr = 0.f;
  for (int k = 0; k < 8; ++k) {
    float m = masks[((u64)k*2048 + i)*2048 + j];
    float dv = 0.f;
    #pragma unroll
    for (int r = 0; r < 16; ++r) dv += tS[k][ii][r]*vS[k][jj][r];
    corr += alpha[k]*m*dv;
  }
  float val = adj[(u64)i*2048 + j] + corr;
  oadj[(u64)i*2048 + j] = val;
  out0[(u64)i*2048 + j] = val;
}

__global__ void kFinal(const float* __restrict__ C, float* __restrict__ out1) {
  int gid = blockIdx.x*256 + threadIdx.x;
  if (gid >= 2048*2048) return;
  int i = gid >> 11, j = gid & 2047;
  float v;
  if (i == j) v = 1.0f;
  else v = 0.5f*(C[gid] + C[(u64)j*2048 + i]);
  out1[gid] = fabsf(v);
}

// ================= host =================

extern "C" void kernel_launch(void* const* d_in, const int* in_sizes, int n_in,
                              void* d_out, int out_size, void* d_ws, size_t ws_size,
                              hipStream_t stream) {
  const float* A      = (const float*)d_in[0];
  const float* X      = (const float*)d_in[1];
  const float* W      = (const float*)d_in[2];
  const float* Us     = (const float*)d_in[3];
  const float* Vs     = (const float*)d_in[4];
  const float* alphas = (const float*)d_in[5];
  const float* masks  = (const float*)d_in[6];

  char* ws = (char*)d_ws;
  double* A64  = (double*)(ws + OFF_A64);
  float*  Vt   = (float*) (ws + OFF_VT);
  double* tau  = (double*)(ws + OFF_TAU);
  double* d64  = (double*)(ws + OFF_D64);
  double* e64  = (double*)(ws + OFF_E64);
  double* p64  = (double*)(ws + OFF_P64);
  double* w64  = (double*)(ws + OFF_W64);
  double* vbuf = (double*)(ws + OFF_VBUF);
  double* xbuf = (double*)(ws + OFF_XBUF);
  double* y1b  = (double*)(ws + OFF_Y1);
  double* y2b  = (double*)(ws + OFF_Y2);
  double* SCD  = (double*)(ws + OFF_SCD);
  int*    SCI  = (int*)   (ws + OFF_SCI);
  int*    KN   = (int*)   (ws + OFF_KN);
  double* KND  = (double*)(ws + OFF_KND);
  float*  ALPH = (float*) (ws + OFF_ALPHA);
  float*  Qa   = (float*) (ws + OFF_QA);
  float*  Qb   = (float*) (ws + OFF_QB);
  float*  Shat = (float*) (ws + OFF_SHAT);
  float*  Wc   = (float*) (ws + OFF_WC);
  float*  M1   = (float*) (ws + OFF_M1);
  float*  T8   = (float*) (ws + OFF_T8);
  float*  ADJ  = (float*) (ws + OFF_ADJ);
  float*  OADJ = (float*) (ws + OFF_OADJ);
  float*  CB   = (float*) (ws + OFF_CBUF);

  float* out0 = (float*)d_out;                 // reference outputs are float32
  float* out1 = out0 + (u64)2048*2048;

  // --- tridiagonalization (fused Householder, lower, f64) ---
  kCopyA<<<4096, 256, 0, stream>>>(A, A64);
  kInitTri<<<1, 256, 0, stream>>>(A64, vbuf, w64, xbuf);
  for (int i = 0; i < 1023; ++i) {
    int m2 = 1023 - i;
    kBig<<<(m2 + 3)/4, 256, 0, stream>>>(A64, vbuf, w64, xbuf, y1b, y2b, d64, i);
    kSmall<<<1, 256, 0, stream>>>(xbuf, y1b, y2b, vbuf, w64, p64, tau, e64, Vt, i);
  }
  kEpi<<<1, 64, 0, stream>>>(A64, d64);

  // --- D&C: cuts, leaves, merges ---
  kCuts<<<1, 64, 0, stream>>>(d64, e64);
  hipMemsetAsync(Qa, 0, (size_t)4*MBYTE, stream);
  kLeaf<<<64, 64, 0, stream>>>(d64, e64, Qa);

  for (int lvl = 0; lvl < 6; ++lvl) {
    int bs = 16 << lvl;
    int nm = 2*bs;
    int cnt = 1024/nm;
    for (int mg = 0; mg < cnt; ++mg) {
      int lo = mg*nm;
      kDeflate2<<<1, 1024, 0, stream>>>(Qa, d64, e64, SCD, SCI, KN, KND, lo, bs, nm);
      kRots<<<(nm + 255)/256, 256, 0, stream>>>(Qa, SCD, SCI, KN, lo, nm);
      kSecular2<<<(nm + 3)/4, 256, 0, stream>>>(SCD, KN, KND, nm);
      kZhat<<<(nm + 63)/64, 64, 0, stream>>>(SCD, KN, nm);
      kSvecNorm<<<nm, 256, 0, stream>>>(Shat, SCD, KN, nm);
      kSortPerm<<<1, 1024, 0, stream>>>(SCD, SCI, KN, d64, lo, nm);
      kGather<<<(nm*nm + 255)/256, 256, 0, stream>>>(Qa, Qb, SCI, KN, lo, nm);
      dim3 gg(nm/16, nm/16);
      kGemmMerge<<<gg, dim3(16, 16), 0, stream>>>(Qb, Shat, Qa, SCI, KN, lo, nm);
      kScatterDefl<<<(nm*nm + 255)/256, 256, 0, stream>>>(Qb, Qa, SCI, KN, lo, nm);
    }
  }

  // --- back-transform: Qa = U (eigenvectors of A, ascending) ---
  kBackx<<<64, 256, 0, stream>>>(Qa, Vt, tau);

  // --- downstream pipeline ---
  kWc<<<8192, 256, 0, stream>>>(W, Wc);
  // M1 = U^T @ X  (1024 x 2048)
  gemm_f32<1,0><<<dim3(32, 16), 256, 0, stream>>>(Qa, X, M1, 1024, 2048, 1024, 1024, 2048, 2048);
  // f_d = Wc @ M1 (2048 x 2048) -> ADJ
  gemm_f32<0,0><<<dim3(32, 32), 256, 0, stream>>>(Wc, M1, ADJ, 2048, 2048, 1024, 1024, 2048, 2048);
  kAbsDiag<<<16384, 256, 0, stream>>>(ADJ);
  kTk<<<dim3(128, 8), 256, 0, stream>>>(ADJ, masks, Us, T8);
  kAlpha<<<1, 64, 0, stream>>>(alphas, ALPH);
  kOutAdj<<<dim3(128, 128), 256, 0, stream>>>(ADJ, masks, Vs, T8, ALPH, OADJ, out0);
  // C = out_adj @ out_adj^T
  gemm_f32<0,1><<<dim3(32, 32), 256, 0, stream>>>(OADJ, OADJ, CB, 2048, 2048, 2048, 2048, 2048, 2048);
  kFinal<<<16384, 256, 0, stream>>>(CB, out1);
}

// Round 4
// 21498.000 us; speedup vs baseline: 3.9271x; 1.4552x over previous
//
#include <hip/hip_runtime.h>
#include <hip/hip_bf16.h>

typedef unsigned long long u64;

#define MBYTE (1ull << 20)

// ---------------- workspace layout (bytes) ----------------
static const size_t OFF_A64   = 0;                    // 1024^2 f64 (8MB)
static const size_t OFF_VT    = 8*MBYTE;              // 1024^2 f32 (4MB) reflectors transposed
static const size_t OFF_TAU   = 12*MBYTE;             // 1024 f64
static const size_t OFF_D64   = 12*MBYTE +  8192;
static const size_t OFF_E64   = 12*MBYTE + 16384;
static const size_t OFF_XB    = 12*MBYTE + 24576;     // x ping (8KB)
static const size_t OFF_Y2B   = 12*MBYTE + 32768;     // y2 pong
static const size_t OFF_Y1B   = 12*MBYTE + 40960;     // y1 pong
static const size_t OFF_XA    = 12*MBYTE + 49152;     // x pong
static const size_t OFF_Y1A   = 12*MBYTE + 57344;     // y1 ping
static const size_t OFF_Y2A   = 12*MBYTE + 65536;     // y2 ping
static const size_t OFF_QA    = 13*MBYTE;             // 4MB f32 (D&C Q, later U)
static const size_t OFF_QB    = 17*MBYTE;             // 4MB f32
static const size_t OFF_SHAT  = 21*MBYTE;             // 4MB f32
static const size_t OFF_WC    = 25*MBYTE;             // 8MB f32; during D&C holds batched merge scratch
static const size_t OFF_M1    = 33*MBYTE;             // 8MB f32
static const size_t OFF_T8    = 33*MBYTE;             // 2MB f32 (reuses M1, dead by then)
static const size_t OFF_ALPHA = 35*MBYTE + 512*1024;  // float[8] (dead region)
static const size_t OFF_ADJ   = 41*MBYTE;             // 16MB f32
static const size_t OFF_OADJ  = 17*MBYTE;             // 16MB f32 (reuses QB/SHAT/WC, dead)
static const size_t OFF_CBUF  = 0;                    // 16MB f32 (reuses A64/VT/QA, dead)

// batched D&C scratch inside the (dead-during-D&C) WC region
static const size_t SCD_STRIDE = 9216;   // doubles per merge
static const size_t SCI_STRIDE = 6144;   // ints per merge
static const size_t OFF_SCDB  = OFF_WC;                       // 32*9216*8 = 2359296
static const size_t OFF_SCIB  = OFF_WC + 2359296;             // 32*6144*4 = 786432
static const size_t OFF_KNB   = OFF_WC + 2359296 + 786432;    // 32*8 ints
static const size_t OFF_KNDB  = OFF_WC + 2359296 + 786432 + 2048; // 32*4 dbl

// ================= tridiagonalization (ssytd2-faithful, lower, f64) =================
// One fused kernel per reflector step i:
//   Phase A (i>=1): EVERY block redundantly recomputes the "small" phase of
//   reflector i-1 (norm/beta/tau, v, P, w, next pivot column x_i) in LDS from
//   the global y1/y2/x of the previous launch. Bitwise-identical thread maps
//   to the old kSmall so the eigen decision path is unchanged. Block 0 also
//   writes Vt row, tau, e, d64, and x_i (ping-pong buffer).
//   Phase B: rank-2 apply of reflector i-1 to rows>=i+1 fused with
//   y1/y2 = A'*x_i computation (as before).

__global__ void kCopyA(const float* __restrict__ A, double* __restrict__ A64) {
  int gid = blockIdx.x*256 + threadIdx.x;
  if (gid < 1024*1024) A64[gid] = (double)A[gid];
}

__global__ void kInitTri(const double* __restrict__ A64, double* xa) {
  int tid = threadIdx.x;
  for (int c = 1 + tid; c < 1024; c += 256) xa[c] = A64[(u64)c*1024 + 0];
}

__global__ __launch_bounds__(256) void kStep(double* __restrict__ A64,
    const double* __restrict__ xin, double* __restrict__ xout,
    const double* __restrict__ y1in, const double* __restrict__ y2in,
    double* __restrict__ y1out, double* __restrict__ y2out,
    double* __restrict__ tauv, double* __restrict__ e64, double* __restrict__ d64,
    float* __restrict__ Vt, int i) {
  __shared__ double xL[1024], vL[1024], wL[1024];
  __shared__ double red[256];
  __shared__ double sS[4];
  int tid = threadIdx.x;
  bool w0 = (blockIdx.x == 0);
  if (i == 0) {
    for (int c = tid; c < 1024; c += 256) { vL[c] = 0.0; wL[c] = 0.0; }
    for (int c = 1 + tid; c < 1024; c += 256) xL[c] = xin[c];
    if (w0 && tid == 0) d64[0] = A64[0];
    __syncthreads();
  } else {
    int j = i - 1;                       // reflector being finalized
    for (int c = i + tid; c < 1024; c += 256) xL[c] = xin[c];
    __syncthreads();
    double acc = 0.0;
    for (int c = i + 1 + tid; c < 1024; c += 256) { double v = xL[c]; acc += v*v; }
    red[tid] = acc; __syncthreads();
    for (int s = 128; s > 0; s >>= 1) { if (tid < s) red[tid] += red[tid+s]; __syncthreads(); }
    if (tid == 0) {
      double xn2 = red[0];
      double alpha = xL[i];
      double tv, sc;
      if (xn2 == 0.0) { tv = 0.0; if (w0) e64[j] = alpha; sc = 0.0; }
      else {
        double beta = (alpha >= 0.0) ? -sqrt(alpha*alpha + xn2) : sqrt(alpha*alpha + xn2);
        tv = (beta - alpha)/beta;
        if (w0) e64[j] = beta;
        sc = 1.0/(alpha - beta);
      }
      if (w0) tauv[j] = tv;
      sS[0] = sc; sS[1] = tv;
      vL[i] = 1.0;
      if (w0) Vt[(u64)j*1024 + i] = 1.0f;
    }
    __syncthreads();
    double sc = sS[0], tv = sS[1];
    for (int c = i + 1 + tid; c < 1024; c += 256) {
      double v = xL[c]*sc;
      vL[c] = v;
      if (w0) Vt[(u64)j*1024 + c] = (float)v;
    }
    __syncthreads();
    double acc2 = 0.0;
    for (int r = i + tid; r < 1024; r += 256) {
      double P = tv*(y1in[r] + sc*y2in[r]);
      wL[r] = P;
      acc2 += P*vL[r];
    }
    red[tid] = acc2; __syncthreads();
    for (int s = 128; s > 0; s >>= 1) { if (tid < s) red[tid] += red[tid+s]; __syncthreads(); }
    if (tid == 0) sS[2] = 0.5*tv*red[0];
    __syncthreads();
    double coef = sS[2];
    for (int r = i + tid; r < 1024; r += 256) wL[r] = wL[r] - coef*vL[r];
    __syncthreads();
    double wi = wL[i];
    for (int c = i + 1 + tid; c < 1024; c += 256) {
      double nx = y1in[c] - vL[c]*wi - wL[c];
      xL[c] = nx;
      if (w0) xout[c] = nx;
    }
    if (tid == 0 && w0) d64[i] = A64[(u64)i*1024 + i] - 2.0*wL[i];
    __syncthreads();
  }
  // Phase B
  if (i <= 1022) {
    int wave = tid >> 6, lane = tid & 63;
    int r = i + 1 + blockIdx.x*4 + wave;
    if (r <= 1023) {
      double vr = vL[r], wr = wL[r];
      double* Arow = A64 + (u64)r*1024;
      double acc = 0.0, y1v = 0.0;
      for (int c = i + 1 + lane; c < 1024; c += 64) {
        double a = Arow[c] - vr*wL[c] - wr*vL[c];
        Arow[c] = a;
        if (c == i + 1) y1v = a; else acc += a*xL[c];
      }
      for (int off = 32; off > 0; off >>= 1) acc += __shfl_down(acc, off);
      if (lane == 0) { y1out[r] = y1v; y2out[r] = acc; }
    }
  }
}

__global__ void kCuts(double* d64, const double* e64) {
  if (threadIdx.x == 0 && blockIdx.x == 0) {
    for (int c = 16; c < 1024; c += 16) {
      double ae = fabs(e64[c-1]);
      d64[c-1] -= ae;
      d64[c]   -= ae;
    }
  }
}

// ================= ssteqr (leaves, n=16, COMPZ='I') =================

__device__ void slartg_(double f, double g, double* cs, double* sn, double* r) {
  if (g == 0.0) { *cs = 1.0; *sn = 0.0; *r = f; }
  else if (f == 0.0) { *cs = 0.0; *sn = (g >= 0.0) ? 1.0 : -1.0; *r = fabs(g); }
  else {
    double d = sqrt(f*f + g*g);
    *cs = fabs(f)/d;
    *r = (f >= 0.0) ? d : -d;
    *sn = g / (*r);
  }
}

__device__ void slaev2_(double a, double b, double c, double* rt1, double* rt2,
                        double* cs1, double* sn1) {
  double sm = a + c, df = a - c, adf = fabs(df), tb = b + b, ab = fabs(tb);
  double acmx, acmn;
  if (fabs(a) > fabs(c)) { acmx = a; acmn = c; } else { acmx = c; acmn = a; }
  double rt;
  if (adf > ab) rt = adf*sqrt(1.0 + (ab/adf)*(ab/adf));
  else if (adf < ab) rt = ab*sqrt(1.0 + (adf/ab)*(adf/ab));
  else rt = ab*sqrt(2.0);
  int sgn1;
  if (sm < 0.0) { *rt1 = 0.5*(sm - rt); sgn1 = -1; *rt2 = (acmx / *rt1)*acmn - (b / *rt1)*b; }
  else if (sm > 0.0) { *rt1 = 0.5*(sm + rt); sgn1 = 1; *rt2 = (acmx / *rt1)*acmn - (b / *rt1)*b; }
  else { *rt1 = 0.5*rt; *rt2 = -0.5*rt; sgn1 = 1; }
  int sgn2; double cs;
  if (df >= 0.0) { cs = df + rt; sgn2 = 1; } else { cs = df - rt; sgn2 = -1; }
  double acs = fabs(cs);
  if (acs > ab) { double ct = -tb/cs; *sn1 = 1.0/sqrt(1.0 + ct*ct); *cs1 = ct*(*sn1); }
  else {
    if (ab == 0.0) { *cs1 = 1.0; *sn1 = 0.0; }
    else { double tn = -cs/tb; *cs1 = 1.0/sqrt(1.0 + tn*tn); *sn1 = tn*(*cs1); }
  }
  if (sgn1 == sgn2) { double tn = *cs1; *cs1 = -(*sn1); *sn1 = tn; }
}

__device__ void steqr16_(double* d, double* e, double* z, double* wc, double* ws_) {
  const int n = 16;
  const double eps = 5.9604644775390625e-08;
  const double eps2 = eps*eps;
  const double safmin = 1.1754943508222875e-38;
  int jtot = 0; const int nmaxit = n*30;
  int l1 = 0;
  for (int outer = 0; outer < 200; ++outer) {
    if (l1 > n-1) break;
    if (l1 > 0) e[l1-1] = 0.0;
    int m = l1;
    for (; m <= n-2; ++m) {
      double tst = fabs(e[m]);
      if (tst == 0.0) break;
      if (tst <= (sqrt(fabs(d[m]))*sqrt(fabs(d[m+1])))*eps) { e[m] = 0.0; break; }
    }
    int l = l1, lend = m;
    l1 = m + 1;
    if (lend == l) continue;
    if (fabs(d[lend]) < fabs(d[l])) { int t = l; l = lend; lend = t; }
    if (lend > l) {
      for (int it = 0; it < 800; ++it) {
        int mm = lend;
        if (l != lend) {
          for (mm = l; mm <= lend-1; ++mm) {
            double tst = e[mm]*e[mm];
            if (tst <= eps2*fabs(d[mm])*fabs(d[mm+1]) + safmin) break;
          }
        }
        if (mm < lend) e[mm] = 0.0;
        double p = d[l];
        if (mm == l) { d[l] = p; ++l; if (l <= lend) continue; break; }
        if (mm == l+1) {
          double rt1, rt2, c2, s2;
          slaev2_(d[l], e[l], d[l+1], &rt1, &rt2, &c2, &s2);
          for (int r = 0; r < n; ++r) {
            double t = z[r*16 + l + 1];
            z[r*16 + l + 1] = c2*t - s2*z[r*16 + l];
            z[r*16 + l]     = s2*t + c2*z[r*16 + l];
          }
          d[l] = rt1; d[l+1] = rt2; e[l] = 0.0;
          l += 2; if (l <= lend) continue; break;
        }
        if (jtot == nmaxit) break;
        ++jtot;
        double g = (d[l+1] - p)/(2.0*e[l]);
        double r_ = sqrt(g*g + 1.0);
        g = d[mm] - p + e[l]/(g + ((g >= 0.0) ? r_ : -r_));
        double s = 1.0, c = 1.0;
        p = 0.0;
        for (int i = mm-1; i >= l; --i) {
          double f = s*e[i], b = c*e[i];
          double cs, sn, rr;
          slartg_(g, f, &cs, &sn, &rr);
          c = cs; s = sn;
          if (i != mm-1) e[i+1] = rr;
          g = d[i+1] - p;
          rr = (d[i] - g)*s + 2.0*c*b;
          p = s*rr;
          d[i+1] = g + p;
          g = c*rr - b;
          wc[i] = c; ws_[i] = -s;
        }
        for (int jj = mm-1; jj >= l; --jj) {
          double cs = wc[jj], sn = ws_[jj];
          for (int r = 0; r < n; ++r) {
            double t = z[r*16 + jj + 1];
            z[r*16 + jj + 1] = cs*t - sn*z[r*16 + jj];
            z[r*16 + jj]     = sn*t + cs*z[r*16 + jj];
          }
        }
        d[l] -= p;
        e[l] = g;
      }
    } else {
      for (int it = 0; it < 800; ++it) {
        int mm = lend;
        if (l != lend) {
          for (mm = l; mm >= lend+1; --mm) {
            double tst = e[mm-1]*e[mm-1];
            if (tst <= eps2*fabs(d[mm])*fabs(d[mm-1]) + safmin) break;
          }
        }
        if (mm > lend) e[mm-1] = 0.0;
        double p = d[l];
        if (mm == l) { d[l] = p; --l; if (l >= lend) continue; break; }
        if (mm == l-1) {
          double rt1, rt2, c2, s2;
          slaev2_(d[l-1], e[l-1], d[l], &rt1, &rt2, &c2, &s2);
          for (int r = 0; r < n; ++r) {
            double t = z[r*16 + l];
            z[r*16 + l]     = c2*t - s2*z[r*16 + l - 1];
            z[r*16 + l - 1] = s2*t + c2*z[r*16 + l - 1];
          }
          d[l-1] = rt1; d[l] = rt2; e[l-1] = 0.0;
          l -= 2; if (l >= lend) continue; break;
        }
        if (jtot == nmaxit) break;
        ++jtot;
        double g = (d[l-1] - p)/(2.0*e[l-1]);
        double r_ = sqrt(g*g + 1.0);
        g = d[mm] - p + e[l-1]/(g + ((g >= 0.0) ? r_ : -r_));
        double s = 1.0, c = 1.0;
        p = 0.0;
        for (int i = mm; i <= l-1; ++i) {
          double f = s*e[i], b = c*e[i];
          double cs, sn, rr;
          slartg_(g, f, &cs, &sn, &rr);
          c = cs; s = sn;
          if (i != mm) e[i-1] = rr;
          g = d[i] - p;
          rr = (d[i+1] - g)*s + 2.0*c*b;
          p = s*rr;
          d[i] = g + p;
          g = c*rr - b;
          wc[i] = c; ws_[i] = s;
        }
        for (int jj = mm; jj <= l-1; ++jj) {
          double cs = wc[jj], sn = ws_[jj];
          for (int r = 0; r < n; ++r) {
            double t = z[r*16 + jj + 1];
            z[r*16 + jj + 1] = cs*t - sn*z[r*16 + jj];
            z[r*16 + jj]     = sn*t + cs*z[r*16 + jj];
          }
        }
        d[l] -= p;
        e[l-1] = g;
      }
    }
  }
  for (int ii = 1; ii <= n-1; ++ii) {
    int i = ii - 1, k = i;
    double p = d[i];
    for (int j = ii; j <= n-1; ++j) if (d[j] < p) { k = j; p = d[j]; }
    if (k != i) {
      d[k] = d[i]; d[i] = p;
      for (int r = 0; r < n; ++r) { double t = z[r*16 + i]; z[r*16 + i] = z[r*16 + k]; z[r*16 + k] = t; }
    }
  }
}

__global__ void kLeaf(double* d64, const double* e64, float* Qa) {
  __shared__ double dd[16], ed[16], zd[256], wk1[16], wk2[16];
  int leaf = blockIdx.x, lo = leaf*16, tid = threadIdx.x;
  for (int idx = tid; idx < 256; idx += 64) zd[idx] = ((idx/16) == (idx%16)) ? 1.0 : 0.0;
  if (tid < 16) { dd[tid] = d64[lo + tid]; ed[tid] = (tid < 15) ? e64[lo + tid] : 0.0; }
  __syncthreads();
  if (tid == 0) steqr16_(dd, ed, zd, wk1, wk2);
  __syncthreads();
  for (int idx = tid; idx < 256; idx += 64) {
    int r = idx/16, c = idx%16;
    Qa[(u64)(lo + r)*1024 + lo + c] = (float)zd[idx];
  }
  if (tid < 16) d64[lo + tid] = dd[tid];
}

// ================= batched D&C merge =================
// scd per-merge (doubles): 1024 dl | 2048 wm | 3072 mu | 4096 zh | 7168 dval
// sci per-merge (ints):    0 permsec | 1024 deflc | 4096 rootpos | 5120 dpos

__global__ __launch_bounds__(1024) void kDeflateB(float* __restrict__ Qa,
      const double* __restrict__ d64, const double* __restrict__ e64,
      double* scdB, int* sciB, int* knB, double* kndB, int bs) {
  __shared__ double zL[1024], dlocL[1024], redD[1024];
  __shared__ double rcL[1024], rsL[1024];
  __shared__ int sIdxL[1024], rpqL[1024];
  __shared__ double sSc[4];
  __shared__ int sKn[4];
  int mg = blockIdx.x;
  int n1 = bs, n = 2*bs, lo = mg*n;
  double* scd = scdB + (u64)mg*SCD_STRIDE;
  int*    sci = sciB + (u64)mg*SCI_STRIDE;
  int* kn = knB + mg*8;
  double* knd = kndB + mg*4;
  int tid = threadIdx.x;
  if (tid == 0) sSc[0] = e64[lo + n1 - 1];
  __syncthreads();
  double rho_in = sSc[0];
  const double invs2 = 0.70710678118654752440;
  if (tid < n) {
    int row = (tid < n1) ? (lo + n1 - 1) : (lo + n1);
    double s = (rho_in < 0.0 && tid >= n1) ? -invs2 : invs2;
    zL[tid] = (double)Qa[(u64)row*1024 + lo + tid] * s;
    dlocL[tid] = d64[lo + tid];
  }
  __syncthreads();
  if (tid < n) {
    int pos; double key = dlocL[tid];
    if (tid < n1) {
      int loB = 0, hiB = n - n1;
      while (loB < hiB) { int mid = (loB+hiB)>>1; if (dlocL[n1+mid] < key) loB = mid+1; else hiB = mid; }
      pos = tid + loB;
    } else {
      int loA = 0, hiA = n1;
      while (loA < hiA) { int mid = (loA+hiA)>>1; if (dlocL[mid] <= key) loA = mid+1; else hiA = mid; }
      pos = (tid - n1) + loA;
    }
    sIdxL[pos] = tid;
  }
  redD[tid] = (tid < n) ? fabs(zL[tid]) : 0.0;
  __syncthreads();
  for (int s = 512; s > 0; s >>= 1) { if (tid < s) redD[tid] = fmax(redD[tid], redD[tid+s]); __syncthreads(); }
  if (tid == 0) sSc[1] = redD[0];
  __syncthreads();
  redD[tid] = (tid < n) ? fabs(dlocL[tid]) : 0.0;
  __syncthreads();
  for (int s = 512; s > 0; s >>= 1) { if (tid < s) redD[tid] = fmax(redD[tid], redD[tid+s]); __syncthreads(); }
  if (tid == 0) {
    double zmax = sSc[1], dmax = redD[0];
    double rho = fabs(2.0*rho_in);
    double tol = 8.0*5.9604644775390625e-8*fmax(dmax, zmax);
    double* dlG = scd + 1024;
    double* wmG = scd + 2048;
    double* dvalG = scd + 7168;
    int* permG = sci;
    int* deflG = sci + 1024;
    int K = 0, nrot = 0, nd = 0; double sw2 = 0.0;
    if (rho*zmax <= tol) {
      for (int pos = 0; pos < n; ++pos) { int c = sIdxL[pos]; deflG[nd] = c; dvalG[nd] = dlocL[c]; nd++; }
    } else {
      int pj = -1, jpos = 0;
      for (; jpos < n; ++jpos) {
        int nj = sIdxL[jpos];
        if (rho*fabs(zL[nj]) <= tol) { deflG[nd] = nj; dvalG[nd] = dlocL[nj]; nd++; }
        else { pj = nj; break; }
      }
      for (++jpos; jpos < n; ++jpos) {
        int nj = sIdxL[jpos];
        if (rho*fabs(zL[nj]) <= tol) { deflG[nd] = nj; dvalG[nd] = dlocL[nj]; nd++; continue; }
        double s_ = zL[pj], c_ = zL[nj];
        double tu = sqrt(c_*c_ + s_*s_);
        double tdif = dlocL[nj] - dlocL[pj];
        c_ /= tu; s_ = -s_/tu;
        if (fabs(tdif*c_*s_) <= tol) {
          zL[nj] = tu; zL[pj] = 0.0;
          rpqL[nrot] = (pj << 16) | nj; rcL[nrot] = c_; rsL[nrot] = s_; nrot++;
          double t1 = dlocL[pj]*c_*c_ + dlocL[nj]*s_*s_;
          dlocL[nj] = dlocL[pj]*s_*s_ + dlocL[nj]*c_*c_;
          dlocL[pj] = t1;
          deflG[nd] = pj; dvalG[nd] = t1; nd++;
          pj = nj;
        } else {
          permG[K] = pj; dlG[K] = dlocL[pj]; wmG[K] = zL[pj]; sw2 += zL[pj]*zL[pj]; K++;
          pj = nj;
        }
      }
      permG[K] = pj; dlG[K] = dlocL[pj]; wmG[K] = zL[pj]; sw2 += zL[pj]*zL[pj]; K++;
    }
    sKn[1] = nrot;
    kn[0] = K; kn[1] = nrot; kn[2] = nd;
    knd[0] = rho; knd[1] = sw2;
  }
  __syncthreads();
  int nrot = sKn[1];
  if (tid < n && nrot > 0) {
    u64 row = (u64)(lo + tid)*1024;
    for (int t = 0; t < nrot; ++t) {
      int pq = rpqL[t];
      int p = lo + (pq >> 16), q = lo + (pq & 0xffff);
      double c = rcL[t], s = rsL[t];
      double x = (double)Qa[row + p], y = (double)Qa[row + q];
      Qa[row + p] = (float)(c*x + s*y);
      Qa[row + q] = (float)(c*y - s*x);
    }
  }
}

__global__ __launch_bounds__(256) void kSecularB(double* scdB, const int* knB, const double* kndB) {
  __shared__ double dlS[1024], wmS[1024];
  int mg = blockIdx.y;
  double* scd = scdB + (u64)mg*SCD_STRIDE;
  const int* kn = knB + mg*8;
  const double* knd = kndB + mg*4;
  int K = kn[0];
  int tid = threadIdx.x;
  for (int j = tid; j < K; j += 256) { dlS[j] = scd[1024 + j]; wmS[j] = scd[2048 + j]; }
  __syncthreads();
  int wave = tid >> 6, lane = tid & 63;
  int i = blockIdx.x*4 + wave;
  if (i >= K) return;
  double rho = knd[0], sw2 = knd[1];
  double di = dlS[i];
  double hi = (i < K-1) ? (dlS[i+1] - di) : (rho*sw2*(1.0 + 1e-12) + 1e-300);
  double lo_ = 0.0;
  for (int it = 0; it < 100; ++it) {
    double mid = 0.5*(lo_ + hi);
    double g = 0.0;
    for (int j = lane; j < K; j += 64) { double w = wmS[j]; g += w*w/((dlS[j] - di) - mid); }
    for (int off = 32; off > 0; off >>= 1) g += __shfl_xor(g, off);
    g = 1.0 + rho*g;
    if (g < 0.0) lo_ = mid; else hi = mid;
  }
  scd[3072 + i] = 0.5*(lo_ + hi);
}

__global__ void kZhatB(double* scdB, const int* knB) {
  int mg = blockIdx.y;
  double* scd = scdB + (u64)mg*SCD_STRIDE;
  int K = (knB + mg*8)[0];
  int j = blockIdx.x*64 + threadIdx.x;
  if (j >= K) return;
  const double* dl = scd + 1024;
  const double* wm = scd + 2048;
  const double* mu = scd + 3072;
  double dj = dl[j];
  double prod = mu[j];
  for (int i2 = 0; i2 < K; ++i2) {
    if (i2 == j) continue;
    double dd = dl[i2] - dj;
    prod *= (dd + mu[i2]) / dd;
  }
  prod = fabs(prod);
  scd[4096 + j] = (wm[j] >= 0.0) ? sqrt(prod) : -sqrt(prod);
}

__global__ __launch_bounds__(1024) void kSortPermB(double* scdB, int* sciB, const int* knB,
                                                   double* d64, int bs) {
  __shared__ double sv[1024];
  __shared__ int si[1024];
  int mg = blockIdx.x;
  int n = 2*bs, lo = mg*n;
  double* scd = scdB + (u64)mg*SCD_STRIDE;
  int* sci = sciB + (u64)mg*SCI_STRIDE;
  int K = (knB + mg*8)[0];
  int tid = threadIdx.x;
  const double* dl = scd + 1024;
  const double* mu = scd + 3072;
  const double* dval = scd + 7168;
  double v;
  if (tid < K) v = dl[tid] + mu[tid];
  else if (tid < n) v = dval[tid - K];
  else v = 1e300;
  sv[tid] = v; si[tid] = tid;
  __syncthreads();
  for (int k = 2; k <= 1024; k <<= 1) {
    for (int j = k >> 1; j > 0; j >>= 1) {
      int ixj = tid ^ j;
      if (ixj > tid) {
        bool up = ((tid & k) == 0);
        double a = sv[tid], b = sv[ixj];
        int ia = si[tid], ib = si[ixj];
        bool agtb = (a > b) || (a == b && ia > ib);
        if (up ? agtb : !agtb) { sv[tid] = b; sv[ixj] = a; si[tid] = ib; si[ixj] = ia; }
      }
      __syncthreads();
    }
  }
  if (tid < n) {
    int s = si[tid];
    if (s < K) sci[4096 + s] = tid; else sci[5120 + s - K] = tid;
    d64[lo + tid] = sv[tid];
  }
}

__global__ void kSvecNormB(float* __restrict__ Shat, const double* scdB, const int* knB, int bs) {
  int mg = blockIdx.y;
  int n = 2*bs, lo = mg*n;
  const double* scd = scdB + (u64)mg*SCD_STRIDE;
  int K = (knB + mg*8)[0];
  int i = blockIdx.x;
  if (i >= K) return;
  const double* dl = scd + 1024;
  const double* mu = scd + 3072;
  const double* zh = scd + 4096;
  __shared__ double red[256];
  int tid = threadIdx.x;
  double di = dl[i], m = mu[i];
  double acc = 0.0;
  for (int j = tid; j < K; j += 256) {
    double v = zh[j]/((dl[j] - di) - m);
    acc += v*v;
  }
  red[tid] = acc; __syncthreads();
  for (int s = 128; s > 0; s >>= 1) { if (tid < s) red[tid] += red[tid+s]; __syncthreads(); }
  double inv = 1.0/sqrt(red[0]);
  for (int j = tid; j < K; j += 256) {
    double v = zh[j]/((dl[j] - di) - m);
    Shat[(u64)j*1024 + lo + i] = (float)(v*inv);
  }
}

__global__ void kGatherB(const float* Qa, float* Qb, const int* sciB, const int* knB, int bs) {
  int mg = blockIdx.y;
  int n = 2*bs, lo = mg*n;
  const int* sci = sciB + (u64)mg*SCI_STRIDE;
  int K = (knB + mg*8)[0];
  int gid = blockIdx.x*256 + threadIdx.x;
  if (gid >= n*n) return;
  int p = gid % n, r = gid / n;
  int src = (p < K) ? sci[p] : sci[1024 + p - K];
  Qb[(u64)(lo + r)*1024 + p] = Qa[(u64)(lo + r)*1024 + lo + src];
}

__global__ void kGemmMergeB(const float* __restrict__ Qb, const float* __restrict__ Shat,
                            float* __restrict__ Qa, const int* sciB, const int* knB, int bs) {
  __shared__ float As[16][17], Bs[16][17];
  int mg = blockIdx.z;
  int n = 2*bs, lo = mg*n;
  const int* sci = sciB + (u64)mg*SCI_STRIDE;
  int K = (knB + mg*8)[0];
  int tx = threadIdx.x, ty = threadIdx.y;
  int r0 = blockIdx.y*16, c0 = blockIdx.x*16;
  const int* rootpos = sci + 4096;
  float acc = 0.f;
  for (int k0 = 0; k0 < K; k0 += 16) {
    As[ty][tx] = (k0 + tx < K) ? Qb[(u64)(lo + r0 + ty)*1024 + k0 + tx] : 0.f;
    Bs[ty][tx] = (k0 + ty < K && c0 + tx < K) ? Shat[(u64)(k0 + ty)*1024 + lo + c0 + tx] : 0.f;
    __syncthreads();
    #pragma unroll
    for (int kk = 0; kk < 16; ++kk) acc += As[ty][kk]*Bs[kk][tx];
    __syncthreads();
  }
  int i = c0 + tx;
  if (i < K) Qa[(u64)(lo + r0 + ty)*1024 + lo + rootpos[i]] = acc;
}

__global__ void kScatterDeflB(const float* Qb, float* Qa, const int* sciB, const int* knB, int bs) {
  int mg = blockIdx.y;
  int n = 2*bs, lo = mg*n;
  const int* sci = sciB + (u64)mg*SCI_STRIDE;
  const int* kn = knB + mg*8;
  int gid = blockIdx.x*256 + threadIdx.x;
  if (gid >= n*n) return;
  int p = gid % n, r = gid / n;
  int K = kn[0], nd = kn[2];
  if (p < K || p - K >= nd) return;
  Qa[(u64)(lo + r)*1024 + lo + sci[5120 + p - K]] = Qb[(u64)(lo + r)*1024 + p];
}

// ================= back-transform =================
__global__ void kBackx(float* __restrict__ Qa, const float* __restrict__ Vt,
                       const double* __restrict__ tau) {
  __shared__ double red[256];
  __shared__ double stot[16];
  int tid = threadIdx.x;
  int cix = tid & 15, strip = tid >> 4;
  int col = blockIdx.x*16 + cix;
  for (int i = 1022; i >= 0; --i) {
    int m0 = i + 1;
    double s = 0.0;
    for (int r = m0 + strip; r < 1024; r += 16)
      s += (double)Vt[(u64)i*1024 + r] * (double)Qa[(u64)r*1024 + col];
    red[tid] = s;
    __syncthreads();
    if (tid < 16) {
      double tot = 0.0;
      for (int u = 0; u < 16; ++u) tot += red[u*16 + tid];
      stot[tid] = tot * tau[i];
    }
    __syncthreads();
    double f = stot[cix];
    for (int r = m0 + strip; r < 1024; r += 16)
      Qa[(u64)r*1024 + col] -= (float)(f * (double)Vt[(u64)i*1024 + r]);
    __syncthreads();
  }
}

// ================= downstream math =================

// 128x128 tile, 8x8 micro-tile, BK=8, float4 everywhere
template<int TA, int TB>
__global__ __launch_bounds__(256) void gemm_f32(const float* __restrict__ A,
    const float* __restrict__ B, float* __restrict__ C,
    int M, int N, int Kd, int lda, int ldb, int ldc) {
  __shared__ float As[8][132];
  __shared__ float Bs[8][132];
  int tid = threadIdx.x;
  int bi = blockIdx.y*128, bj = blockIdx.x*128;
  int tx = tid & 15, ty = tid >> 4;
  float acc[8][8];
  #pragma unroll
  for (int x = 0; x < 8; ++x)
    #pragma unroll
    for (int y = 0; y < 8; ++y) acc[x][y] = 0.f;
  for (int k0 = 0; k0 < Kd; k0 += 8) {
    if (TA == 0) {
      int row = tid >> 1, kc = (tid & 1)*4;
      float4 v = *(const float4*)&A[(u64)(bi + row)*lda + k0 + kc];
      As[kc+0][row] = v.x; As[kc+1][row] = v.y; As[kc+2][row] = v.z; As[kc+3][row] = v.w;
    } else {
      int kk = tid >> 5, col = (tid & 31)*4;
      float4 v = *(const float4*)&A[(u64)(k0 + kk)*lda + bi + col];
      *(float4*)&As[kk][col] = v;
    }
    if (TB == 0) {
      int kk = tid >> 5, col = (tid & 31)*4;
      float4 v = *(const float4*)&B[(u64)(k0 + kk)*ldb + bj + col];
      *(float4*)&Bs[kk][col] = v;
    } else {
      int row = tid >> 1, kc = (tid & 1)*4;
      float4 v = *(const float4*)&B[(u64)(bj + row)*ldb + k0 + kc];
      Bs[kc+0][row] = v.x; Bs[kc+1][row] = v.y; Bs[kc+2][row] = v.z; Bs[kc+3][row] = v.w;
    }
    __syncthreads();
    #pragma unroll
    for (int kk = 0; kk < 8; ++kk) {
      float a[8], b[8];
      *(float4*)&a[0] = *(float4*)&As[kk][ty*8];
      *(float4*)&a[4] = *(float4*)&As[kk][ty*8 + 4];
      *(float4*)&b[0] = *(float4*)&Bs[kk][tx*8];
      *(float4*)&b[4] = *(float4*)&Bs[kk][tx*8 + 4];
      #pragma unroll
      for (int x = 0; x < 8; ++x)
        #pragma unroll
        for (int y = 0; y < 8; ++y) acc[x][y] += a[x]*b[y];
    }
    __syncthreads();
  }
  #pragma unroll
  for (int x = 0; x < 8; ++x) {
    float* Crow = &C[(u64)(bi + ty*8 + x)*ldc + bj + tx*8];
    *(float4*)&Crow[0] = make_float4(acc[x][0], acc[x][1], acc[x][2], acc[x][3]);
    *(float4*)&Crow[4] = make_float4(acc[x][4], acc[x][5], acc[x][6], acc[x][7]);
  }
}

__global__ void kWc(const float* W, float* Wc) {
  int gid = blockIdx.x*256 + threadIdx.x;
  if (gid >= 2048*1024) return;
  int i = gid >> 10, k = gid & 1023;
  Wc[gid] = W[(u64)i*2048 + k] + W[(u64)i*2048 + 1024 + k];
}

__global__ void kAbsDiag(float* adj) {
  int gid = blockIdx.x*256 + threadIdx.x;
  if (gid >= 2048*2048) return;
  int i = gid >> 11, j = gid & 2047;
  float v = fabsf(adj[gid]);
  adj[gid] = (i == j) ? 1.0f : v;
}

__global__ void kTk(const float* __restrict__ adj, const float* __restrict__ masks,
                    const float* __restrict__ Us, float* __restrict__ t8) {
  int k = blockIdx.y;
  int i = blockIdx.x*16 + (threadIdx.x >> 4);
  int r = threadIdx.x & 15;
  const float* arow = adj + (u64)i*2048;
  const float* mrow = masks + ((u64)k*2048 + i)*2048;
  const float* uk = Us + (u64)k*2048*16 + r;
  float acc = 0.f;
  for (int j = 0; j < 2048; ++j) acc += arow[j]*mrow[j]*uk[(u64)j*16];
  t8[((u64)k*2048 + i)*16 + r] = acc;
}

__global__ void kAlpha(const float* alphas, float* alpha) {
  if (threadIdx.x == 0 && blockIdx.x == 0) {
    float m = alphas[0];
    for (int k = 1; k < 8; ++k) m = fmaxf(m, alphas[k]);
    float e[8]; float s = 0.f;
    for (int k = 0; k < 8; ++k) { e[k] = expf(alphas[k] - m); s += e[k]; }
    for (int k = 0; k < 8; ++k) alpha[k] = e[k]/s;
  }
}

__global__ void kOutAdj(const float* __restrict__ adj, const float* __restrict__ masks,
                        const float* __restrict__ Vs, const float* __restrict__ t8,
                        const float* __restrict__ alpha, float* __restrict__ oadj,
                        float* __restrict__ out0) {
  __shared__ float tS[8][16][16];
  __shared__ float vS[8][16][16];
  int j0 = blockIdx.x*16, i0 = blockIdx.y*16;
  int tid = threadIdx.x;
  for (int idx = tid; idx < 2048; idx += 256) {
    int k = idx >> 8, rem = idx & 255, row = rem >> 4, r = rem & 15;
    tS[k][row][r] = t8[((u64)k*2048 + i0 + row)*16 + r];
    vS[k][row][r] = Vs[((u64)k*2048 + j0 + row)*16 + r];
  }
  __syncthreads();
  int ii = tid >> 4, jj = tid & 15;
  int i = i0 + ii, j = j0 + jj;
  float corr = 0.f;
  for (int k = 0; k < 8; ++k) {
    float m = masks[((u64)k*2048 + i)*2048 + j];
    float dv = 0.f;
    #pragma unroll
    for (int r = 0; r < 16; ++r) dv += tS[k][ii][r]*vS[k][jj][r];
    corr += alpha[k]*m*dv;
  }
  float val = adj[(u64)i*2048 + j] + corr;
  oadj[(u64)i*2048 + j] = val;
  out0[(u64)i*2048 + j] = val;
}

__global__ void kFinal(const float* __restrict__ C, float* __restrict__ out1) {
  int gid = blockIdx.x*256 + threadIdx.x;
  if (gid >= 2048*2048) return;
  int i = gid >> 11, j = gid & 2047;
  float v;
  if (i == j) v = 1.0f;
  else v = 0.5f*(C[gid] + C[(u64)j*2048 + i]);
  out1[gid] = fabsf(v);
}

// ================= host =================

extern "C" void kernel_launch(void* const* d_in, const int* in_sizes, int n_in,
                              void* d_out, int out_size, void* d_ws, size_t ws_size,
                              hipStream_t stream) {
  const float* A      = (const float*)d_in[0];
  const float* X      = (const float*)d_in[1];
  const float* W      = (const float*)d_in[2];
  const float* Us     = (const float*)d_in[3];
  const float* Vs     = (const float*)d_in[4];
  const float* alphas = (const float*)d_in[5];
  const float* masks  = (const float*)d_in[6];

  char* ws = (char*)d_ws;
  double* A64  = (double*)(ws + OFF_A64);
  float*  Vt   = (float*) (ws + OFF_VT);
  double* tau  = (double*)(ws + OFF_TAU);
  double* d64  = (double*)(ws + OFF_D64);
  double* e64  = (double*)(ws + OFF_E64);
  double* xa   = (double*)(ws + OFF_XA);
  double* xb   = (double*)(ws + OFF_XB);
  double* y1a  = (double*)(ws + OFF_Y1A);
  double* y1b  = (double*)(ws + OFF_Y1B);
  double* y2a  = (double*)(ws + OFF_Y2A);
  double* y2b  = (double*)(ws + OFF_Y2B);
  double* SCDB = (double*)(ws + OFF_SCDB);
  int*    SCIB = (int*)   (ws + OFF_SCIB);
  int*    KNB  = (int*)   (ws + OFF_KNB);
  double* KNDB = (double*)(ws + OFF_KNDB);
  float*  ALPH = (float*) (ws + OFF_ALPHA);
  float*  Qa   = (float*) (ws + OFF_QA);
  float*  Qb   = (float*) (ws + OFF_QB);
  float*  Shat = (float*) (ws + OFF_SHAT);
  float*  Wc   = (float*) (ws + OFF_WC);
  float*  M1   = (float*) (ws + OFF_M1);
  float*  T8   = (float*) (ws + OFF_T8);
  float*  ADJ  = (float*) (ws + OFF_ADJ);
  float*  OADJ = (float*) (ws + OFF_OADJ);
  float*  CB   = (float*) (ws + OFF_CBUF);

  float* out0 = (float*)d_out;                 // reference outputs are float32
  float* out1 = out0 + (u64)2048*2048;

  // --- tridiagonalization (fused 1 launch/step) ---
  kCopyA<<<4096, 256, 0, stream>>>(A, A64);
  kInitTri<<<1, 256, 0, stream>>>(A64, xa);
  double* xpp[2]  = {xa, xb};
  double* y1pp[2] = {y1a, y1b};
  double* y2pp[2] = {y2a, y2b};
  for (int i = 0; i <= 1023; ++i) {
    const double* xi  = (i == 0) ? xa  : xpp[(i-1)&1];
    const double* y1i = (i == 0) ? y1a : y1pp[(i-1)&1];
    const double* y2i = (i == 0) ? y2a : y2pp[(i-1)&1];
    double* xo  = xpp[i&1];
    double* y1o = y1pp[i&1];
    double* y2o = y2pp[i&1];
    int mbig = 1023 - i;
    int nb = (i <= 1022) ? (mbig + 3)/4 : 1;
    kStep<<<nb, 256, 0, stream>>>(A64, xi, xo, y1i, y2i, y1o, y2o, tau, e64, d64, Vt, i);
  }

  // --- D&C: cuts, leaves, batched merges ---
  kCuts<<<1, 64, 0, stream>>>(d64, e64);
  hipMemsetAsync(Qa, 0, (size_t)4*MBYTE, stream);
  kLeaf<<<64, 64, 0, stream>>>(d64, e64, Qa);

  for (int lvl = 0; lvl < 6; ++lvl) {
    int bs = 16 << lvl;
    int n = 2*bs;
    int cnt = 1024/n;
    kDeflateB<<<cnt, 1024, 0, stream>>>(Qa, d64, e64, SCDB, SCIB, KNB, KNDB, bs);
    kSecularB<<<dim3((n + 3)/4, cnt), 256, 0, stream>>>(SCDB, KNB, KNDB);
    kZhatB<<<dim3((n + 63)/64, cnt), 64, 0, stream>>>(SCDB, KNB);
    kSortPermB<<<cnt, 1024, 0, stream>>>(SCDB, SCIB, KNB, d64, bs);
    kSvecNormB<<<dim3(n, cnt), 256, 0, stream>>>(Shat, SCDB, KNB, bs);
    kGatherB<<<dim3((n*n + 255)/256, cnt), 256, 0, stream>>>(Qa, Qb, SCIB, KNB, bs);
    kGemmMergeB<<<dim3(n/16, n/16, cnt), dim3(16, 16), 0, stream>>>(Qb, Shat, Qa, SCIB, KNB, bs);
    kScatterDeflB<<<dim3((n*n + 255)/256, cnt), 256, 0, stream>>>(Qb, Qa, SCIB, KNB, bs);
  }

  // --- back-transform: Qa = U (eigenvectors of A, ascending) ---
  kBackx<<<64, 256, 0, stream>>>(Qa, Vt, tau);

  // --- downstream pipeline ---
  kWc<<<8192, 256, 0, stream>>>(W, Wc);
  // M1 = U^T @ X  (1024 x 2048)
  gemm_f32<1,0><<<dim3(16, 8), 256, 0, stream>>>(Qa, X, M1, 1024, 2048, 1024, 1024, 2048, 2048);
  // f_d = Wc @ M1 (2048 x 2048) -> ADJ
  gemm_f32<0,0><<<dim3(16, 16), 256, 0, stream>>>(Wc, M1, ADJ, 2048, 2048, 1024, 1024, 2048, 2048);
  kAbsDiag<<<16384, 256, 0, stream>>>(ADJ);
  kTk<<<dim3(128, 8), 256, 0, stream>>>(ADJ, masks, Us, T8);
  kAlpha<<<1, 64, 0, stream>>>(alphas, ALPH);
  kOutAdj<<<dim3(128, 128), 256, 0, stream>>>(ADJ, masks, Vs, T8, ALPH, OADJ, out0);
  // C = out_adj @ out_adj^T
  gemm_f32<0,1><<<dim3(16, 16), 256, 0, stream>>>(OADJ, OADJ, CB, 2048, 2048, 2048, 2048, 2048, 2048);
  kFinal<<<16384, 256, 0, stream>>>(CB, out1);
}